// Round 14
// baseline (768.897 us; speedup 1.0000x reference)
//
#include <hip/hip_runtime.h>
#include <hip/hip_bf16.h>

// ---------------------------------------------------------------------------
// SoftBlobGIN round 14: gather reverted to pure form (BN -> cheap bf16 bnrelu
// kernel); mgemm reads BOTH operands direct from global (no B-LDS staging,
// no barrier) -- W is L1/L2-hot.
// ---------------------------------------------------------------------------

#define HH 128
typedef unsigned short u16;
typedef unsigned int u32;
typedef __attribute__((ext_vector_type(8))) short bf16x8;
typedef __attribute__((ext_vector_type(4))) float f32x4;

__device__ __forceinline__ void atomAddF(float* p, float v) { unsafeAtomicAdd(p, v); }

__device__ __forceinline__ u16 f2bf(float f) {          // RNE f32->bf16
    u32 u = __float_as_uint(f);
    u += 0x7fffu + ((u >> 16) & 1u);
    return (u16)(u >> 16);
}
__device__ __forceinline__ float bf2f_lo(u32 u) { return __uint_as_float(u << 16); }
__device__ __forceinline__ float bf2f_hi(u32 u) { return __uint_as_float(u & 0xffff0000u); }
__device__ __forceinline__ void split2(float v, u16& hi, u16& lo) {
    u16 h_ = f2bf(v);
    float hf = __uint_as_float(((u32)h_) << 16);
    hi = h_;
    lo = f2bf(v - hf);
}

#define WTOT (8192 + 6 * 16384)

// ---------------- weight prep ----------------
__global__ void k_prep(const float* __restrict__ inp_w, const float* __restrict__ m1,
                       const float* __restrict__ m2, u16* __restrict__ Whi,
                       u16* __restrict__ Wlo) {
    int b = blockIdx.x;  // 0..6
    int t = threadIdx.x; // 256
    if (b == 0) {
        for (int idx = t; idx < 128 * 64; idx += 256) {
            int c = idx >> 6, k = idx & 63;
            u16 hi, lo;
            split2(inp_w[k * 128 + c], hi, lo);
            Whi[idx] = hi; Wlo[idx] = lo;
        }
    } else {
        const float* W = (b <= 3) ? m1 + (size_t)(b - 1) * 16384
                                  : m2 + (size_t)(b - 4) * 16384;
        u16* dh = Whi + 8192 + (size_t)(b - 1) * 16384;
        u16* dl = Wlo + 8192 + (size_t)(b - 1) * 16384;
        for (int idx = t; idx < 16384; idx += 256) {
            int c = idx >> 7, k = idx & 127;
            u16 hi, lo;
            split2(W[k * 128 + c], hi, lo);
            dh[idx] = hi; dl[idx] = lo;
        }
    }
}

// ---------------- CSR build (4 edges/thread) ----------------
__global__ void k_hist(const int* __restrict__ ei, int* __restrict__ deg, int E) {
    int i4 = blockIdx.x * 256 + threadIdx.x;
    int e0 = i4 * 4;
    if (e0 + 3 < E) {
        int4 d = *(const int4*)(ei + E + e0);
        atomicAdd(&deg[d.x], 1);
        atomicAdd(&deg[d.y], 1);
        atomicAdd(&deg[d.z], 1);
        atomicAdd(&deg[d.w], 1);
    } else {
        for (int e = e0; e < E; e++) atomicAdd(&deg[ei[E + e]], 1);
    }
}

__global__ void k_bsum(const int* __restrict__ deg, int* __restrict__ bsum, int N) {
    int t = threadIdx.x;
    int i = blockIdx.x * 256 + t;
    int v = (i < N) ? deg[i] : 0;
    for (int o = 32; o; o >>= 1) v += __shfl_down(v, o);
    __shared__ int ws_[4];
    if ((t & 63) == 0) ws_[t >> 6] = v;
    __syncthreads();
    if (t == 0) bsum[blockIdx.x] = ws_[0] + ws_[1] + ws_[2] + ws_[3];
}

__global__ void k_scan1(const int* __restrict__ bsum, int* __restrict__ boff,
                        int* __restrict__ rowptrN, int nch) {
    int t = threadIdx.x;  // 256
    int v = (t < nch) ? bsum[t] : 0;
    int l = t & 63, w = t >> 6;
    int sv = v;
    for (int o = 1; o < 64; o <<= 1) { int u = __shfl_up(sv, o); if (l >= o) sv += u; }
    __shared__ int wsum[4];
    if (l == 63) wsum[w] = sv;
    __syncthreads();
    int add = 0;
    for (int j = 0; j < w; j++) add += wsum[j];
    if (t < nch) boff[t] = sv - v + add;
    if (t == nch - 1) *rowptrN = sv + add;
}

__global__ void k_scan2(const int* __restrict__ deg, const int* __restrict__ boff,
                        int* __restrict__ rowptr, int* __restrict__ cursor, int N) {
    int b = blockIdx.x, t = threadIdx.x, i = b * 256 + t;
    int v = (i < N) ? deg[i] : 0;
    int l = t & 63, w = t >> 6;
    int sv = v;
    for (int o = 1; o < 64; o <<= 1) { int u = __shfl_up(sv, o); if (l >= o) sv += u; }
    __shared__ int wsum[4];
    if (l == 63) wsum[w] = sv;
    __syncthreads();
    int add = boff[b];
    for (int j = 0; j < w; j++) add += wsum[j];
    if (i < N) { int e = sv - v + add; rowptr[i] = e; cursor[i] = e; }
}

__global__ void k_fill(const int* __restrict__ ei, int* __restrict__ cursor,
                       int* __restrict__ col, int E) {
    int i4 = blockIdx.x * 256 + threadIdx.x;
    int e0 = i4 * 4;
    if (e0 + 3 < E) {
        int4 s = *(const int4*)(ei + e0);
        int4 d = *(const int4*)(ei + E + e0);
        int p0 = atomicAdd(&cursor[d.x], 1);
        int p1 = atomicAdd(&cursor[d.y], 1);
        int p2 = atomicAdd(&cursor[d.z], 1);
        int p3 = atomicAdd(&cursor[d.w], 1);
        col[p0] = s.x;
        col[p1] = s.y;
        col[p2] = s.z;
        col[p3] = s.w;
    } else {
        for (int e = e0; e < E; e++) {
            int pos = atomicAdd(&cursor[ei[E + e]], 1);
            col[pos] = ei[e];
        }
    }
}

// ---------------- MFMA GEMM: BOTH operands direct from global ---------------
// MODE 0: f32 input | MODE 1: f32 input + bn-relu | MODE 2: bf16 hi/lo input
template <int KD, int MODE, bool STATS, bool FOUT, bool BOUT>
__global__ __launch_bounds__(512) void k_mgemm(
    const float* __restrict__ inf, const u16* __restrict__ inhi,
    const u16* __restrict__ inlo, const u16* __restrict__ Whi,
    const u16* __restrict__ Wlo, const float* __restrict__ bias,
    const float* __restrict__ statsIn, const float* __restrict__ gamma,
    const float* __restrict__ beta, float invN,
    float* __restrict__ out, u16* __restrict__ outb,
    float* __restrict__ statsOut, int Nrows, int ntiles) {
    __shared__ float s_red[2][8][128];
    __shared__ float s_sc[128], s_sh[128];
    const int t = threadIdx.x;
    constexpr int NF = KD / 32;

    if (MODE == 1 && t < 128) {
        float m = statsIn[t] * invN;
        float var = statsIn[128 + t] * invN - m * m;
        float s = gamma[t] * rsqrtf(var + 1e-5f);
        s_sc[t] = s;
        s_sh[t] = beta[t] - m * s;
    }
    if (MODE == 1) __syncthreads();

    const int l = t & 63, w = t >> 6;
    const int c0 = l & 15;
    const int ksub = (l >> 4) * 8;

    for (int tile = blockIdx.x; tile < ntiles; tile += gridDim.x) {
        const int row = tile * 128 + w * 16 + c0;
        const bool rv = row < Nrows;

        // ---- A fragments direct from global ----
        bf16x8 ah[NF], al[NF];
        if (MODE == 2) {
#pragma unroll
            for (int kk = 0; kk < NF; kk++) {
                int k0 = kk * 32 + ksub;
                if (rv) {
                    ah[kk] = *(const bf16x8*)(inhi + (size_t)row * KD + k0);
                    al[kk] = *(const bf16x8*)(inlo + (size_t)row * KD + k0);
                } else {
                    uint4 z = {0, 0, 0, 0};
                    ah[kk] = *(bf16x8*)&z;
                    al[kk] = *(bf16x8*)&z;
                }
            }
        } else {
#pragma unroll
            for (int kk = 0; kk < NF; kk++) {
                int k0 = kk * 32 + ksub;
                float4 v0 = {0.f, 0.f, 0.f, 0.f}, v1 = {0.f, 0.f, 0.f, 0.f};
                if (rv) {
                    v0 = *(const float4*)(inf + (size_t)row * KD + k0);
                    v1 = *(const float4*)(inf + (size_t)row * KD + k0 + 4);
                }
                float vv[8] = {v0.x, v0.y, v0.z, v0.w, v1.x, v1.y, v1.z, v1.w};
                uint4 uh, ul;
                u32* ph = (u32*)&uh;
                u32* pl = (u32*)&ul;
#pragma unroll
                for (int p = 0; p < 4; p++) {
                    float a0 = vv[2 * p], a1 = vv[2 * p + 1];
                    if (MODE == 1) {
                        a0 = fmaxf(a0 * s_sc[k0 + 2 * p] + s_sh[k0 + 2 * p], 0.f);
                        a1 = fmaxf(a1 * s_sc[k0 + 2 * p + 1] + s_sh[k0 + 2 * p + 1], 0.f);
                    }
                    u16 h0, l0, h1, l1;
                    split2(a0, h0, l0);
                    split2(a1, h1, l1);
                    ph[p] = (u32)h0 | ((u32)h1 << 16);
                    pl[p] = (u32)l0 | ((u32)l1 << 16);
                }
                ah[kk] = *(bf16x8*)&uh;
                al[kk] = *(bf16x8*)&ul;
            }
        }

        // ---- MFMA; B fragments direct from global (W is L1/L2-hot) ----
        f32x4 acc[8];
#pragma unroll
        for (int n = 0; n < 8; n++) acc[n] = (f32x4){0.f, 0.f, 0.f, 0.f};
#pragma unroll
        for (int kk = 0; kk < NF; kk++) {
            int k0 = kk * 32 + ksub;
#pragma unroll
            for (int n = 0; n < 8; n++) {
                const size_t boff = (size_t)(n * 16 + c0) * KD + k0;
                bf16x8 bh = *(const bf16x8*)(Whi + boff);
                bf16x8 bl = *(const bf16x8*)(Wlo + boff);
                acc[n] = __builtin_amdgcn_mfma_f32_16x16x32_bf16(ah[kk], bh, acc[n], 0, 0, 0);
                acc[n] = __builtin_amdgcn_mfma_f32_16x16x32_bf16(al[kk], bh, acc[n], 0, 0, 0);
                acc[n] = __builtin_amdgcn_mfma_f32_16x16x32_bf16(ah[kk], bl, acc[n], 0, 0, 0);
            }
        }

        // ---- epilogue ----
        const int rbase = tile * 128 + w * 16 + ((l >> 4) << 2);
#pragma unroll
        for (int n = 0; n < 8; n++) {
            const int colc = n * 16 + c0;
            const float bv = bias[colc];
            float s = 0.f, q = 0.f;
#pragma unroll
            for (int j = 0; j < 4; j++) {
                int gr = rbase + j;
                if (gr < Nrows) {
                    float v = acc[n][j] + bv;
                    if (FOUT) out[(size_t)gr * HH + colc] = v;
                    if (BOUT) outb[(size_t)gr * HH + colc] = f2bf(v);
                    s += v;
                    q += v * v;
                }
            }
            if (STATS) {
                s += __shfl_xor(s, 16); s += __shfl_xor(s, 32);
                q += __shfl_xor(q, 16); q += __shfl_xor(q, 32);
                if (l < 16) {
                    s_red[0][w][n * 16 + l] = s;
                    s_red[1][w][n * 16 + l] = q;
                }
            }
        }
        if (STATS) {
            __syncthreads();
            if (t < 128) {
                float S = 0.f, Q = 0.f;
#pragma unroll
                for (int ww = 0; ww < 8; ww++) { S += s_red[0][ww][t]; Q += s_red[1][ww][t]; }
                atomAddF(&statsOut[t], S);
                atomAddF(&statsOut[HH + t], Q);
            }
            __syncthreads();
        }
    }
}

// ---------------- gather: 2 waves/node, 8-deep unroll (pure, R11 form) ------
__global__ __launch_bounds__(256) void k_gather(
    const u16* __restrict__ hb,
    const int* __restrict__ rowptr, const int* __restrict__ col,
    const float* __restrict__ ew, const float* __restrict__ eb,
    u16* __restrict__ zhi, u16* __restrict__ zlo, int N) {
    __shared__ float2 s_part[2][64];
    const int wv = threadIdx.x >> 6;
    const int lane = threadIdx.x & 63;
    const int node = blockIdx.x * 2 + (wv >> 1);
    const int hf = wv & 1;
    const int c2 = lane * 2;
    float2 acc = {0.f, 0.f};
    const bool valid = node < N;
    float2 ee = {0.f, 0.f};
    if (valid) {
        ee.x = ew[c2] + eb[c2];
        ee.y = ew[c2 + 1] + eb[c2 + 1];
        const int s = rowptr[node], eend = rowptr[node + 1];
        int e = s + hf;
        for (; e + 14 < eend; e += 16) {
            int s0 = col[e], s1 = col[e + 2], s2 = col[e + 4], s3 = col[e + 6];
            int s4 = col[e + 8], s5 = col[e + 10], s6 = col[e + 12], s7 = col[e + 14];
            u32 u0 = *(const u32*)(hb + (size_t)s0 * HH + c2);
            u32 u1 = *(const u32*)(hb + (size_t)s1 * HH + c2);
            u32 u2 = *(const u32*)(hb + (size_t)s2 * HH + c2);
            u32 u3 = *(const u32*)(hb + (size_t)s3 * HH + c2);
            u32 u4 = *(const u32*)(hb + (size_t)s4 * HH + c2);
            u32 u5 = *(const u32*)(hb + (size_t)s5 * HH + c2);
            u32 u6 = *(const u32*)(hb + (size_t)s6 * HH + c2);
            u32 u7 = *(const u32*)(hb + (size_t)s7 * HH + c2);
            acc.x += fmaxf(bf2f_lo(u0) + ee.x, 0.f) + fmaxf(bf2f_lo(u1) + ee.x, 0.f) +
                     fmaxf(bf2f_lo(u2) + ee.x, 0.f) + fmaxf(bf2f_lo(u3) + ee.x, 0.f) +
                     fmaxf(bf2f_lo(u4) + ee.x, 0.f) + fmaxf(bf2f_lo(u5) + ee.x, 0.f) +
                     fmaxf(bf2f_lo(u6) + ee.x, 0.f) + fmaxf(bf2f_lo(u7) + ee.x, 0.f);
            acc.y += fmaxf(bf2f_hi(u0) + ee.y, 0.f) + fmaxf(bf2f_hi(u1) + ee.y, 0.f) +
                     fmaxf(bf2f_hi(u2) + ee.y, 0.f) + fmaxf(bf2f_hi(u3) + ee.y, 0.f) +
                     fmaxf(bf2f_hi(u4) + ee.y, 0.f) + fmaxf(bf2f_hi(u5) + ee.y, 0.f) +
                     fmaxf(bf2f_hi(u6) + ee.y, 0.f) + fmaxf(bf2f_hi(u7) + ee.y, 0.f);
        }
        for (; e + 6 < eend; e += 8) {
            int s0 = col[e], s1 = col[e + 2], s2 = col[e + 4], s3 = col[e + 6];
            u32 u0 = *(const u32*)(hb + (size_t)s0 * HH + c2);
            u32 u1 = *(const u32*)(hb + (size_t)s1 * HH + c2);
            u32 u2 = *(const u32*)(hb + (size_t)s2 * HH + c2);
            u32 u3 = *(const u32*)(hb + (size_t)s3 * HH + c2);
            acc.x += fmaxf(bf2f_lo(u0) + ee.x, 0.f) + fmaxf(bf2f_lo(u1) + ee.x, 0.f) +
                     fmaxf(bf2f_lo(u2) + ee.x, 0.f) + fmaxf(bf2f_lo(u3) + ee.x, 0.f);
            acc.y += fmaxf(bf2f_hi(u0) + ee.y, 0.f) + fmaxf(bf2f_hi(u1) + ee.y, 0.f) +
                     fmaxf(bf2f_hi(u2) + ee.y, 0.f) + fmaxf(bf2f_hi(u3) + ee.y, 0.f);
        }
        for (; e < eend; e += 2) {
            u32 u0 = *(const u32*)(hb + (size_t)col[e] * HH + c2);
            acc.x += fmaxf(bf2f_lo(u0) + ee.x, 0.f);
            acc.y += fmaxf(bf2f_hi(u0) + ee.y, 0.f);
        }
    }
    if (hf) s_part[wv >> 1][lane] = acc;
    __syncthreads();
    if (!hf && valid) {
        float2 p = s_part[wv >> 1][lane];
        u32 un = *(const u32*)(hb + (size_t)node * HH + c2);
        float zx = bf2f_lo(un) + acc.x + p.x;
        float zy = bf2f_hi(un) + acc.y + p.y;
        u16 h0, h1, l0, l1;
        split2(zx, h0, l0);
        split2(zy, h1, l1);
        *(u32*)(zhi + (size_t)node * HH + c2) = (u32)h0 | ((u32)h1 << 16);
        *(u32*)(zlo + (size_t)node * HH + c2) = (u32)l0 | ((u32)l1 << 16);
    }
}

// ---------------- bnrelu bf16->bf16 (layers 0,1): hb = bf16(relu(bn(t2b))) --
__global__ void k_bnrelu_bf(const u16* __restrict__ tb, const float* __restrict__ stats,
                            const float* __restrict__ g, const float* __restrict__ b,
                            float invN, u16* __restrict__ hb, int total4) {
    int i = blockIdx.x * 256 + threadIdx.x;
    if (i >= total4) return;
    int c4 = (i & 31) << 2;
    float sc[4], sh[4];
#pragma unroll
    for (int j = 0; j < 4; j++) {
        float m = stats[c4 + j] * invN;
        float var = stats[128 + c4 + j] * invN - m * m;
        float s = g[c4 + j] * rsqrtf(var + 1e-5f);
        sc[j] = s;
        sh[j] = b[c4 + j] - m * s;
    }
    uint2 v = *(const uint2*)(tb + (size_t)i * 4);
    float o0 = fmaxf(bf2f_lo(v.x) * sc[0] + sh[0], 0.f);
    float o1 = fmaxf(bf2f_hi(v.x) * sc[1] + sh[1], 0.f);
    float o2 = fmaxf(bf2f_lo(v.y) * sc[2] + sh[2], 0.f);
    float o3 = fmaxf(bf2f_hi(v.y) * sc[3] + sh[3], 0.f);
    uint2 p = {(u32)f2bf(o0) | ((u32)f2bf(o1) << 16),
               (u32)f2bf(o2) | ((u32)f2bf(o3) << 16)};
    *(uint2*)(hb + (size_t)i * 4) = p;
}

// ---------------- bnrelu f32 (final layer): h = relu(bn(t2f)) ----------------
__global__ void k_bnrelu(const float* __restrict__ t, const float* __restrict__ stats,
                         const float* __restrict__ g, const float* __restrict__ b,
                         float invN, float* __restrict__ h, int total4) {
    int i = blockIdx.x * 256 + threadIdx.x;
    if (i >= total4) return;
    int c4 = (i & 31) << 2;
    float sc[4], sh[4];
#pragma unroll
    for (int j = 0; j < 4; j++) {
        float m = stats[c4 + j] * invN;
        float var = stats[128 + c4 + j] * invN - m * m;
        float s = g[c4 + j] * rsqrtf(var + 1e-5f);
        sc[j] = s;
        sh[j] = b[c4 + j] - m * s;
    }
    float4 v = *(const float4*)(t + (size_t)i * 4);
    float4 o;
    o.x = fmaxf(v.x * sc[0] + sh[0], 0.f);
    o.y = fmaxf(v.y * sc[1] + sh[1], 0.f);
    o.z = fmaxf(v.z * sc[2] + sh[2], 0.f);
    o.w = fmaxf(v.w * sc[3] + sh[3], 0.f);
    *(float4*)(h + (size_t)i * 4) = o;
}

// ---------------- assign ----------------
__global__ __launch_bounds__(256) void k_assign(
    const float* __restrict__ h, const float* __restrict__ gum,
    const float* __restrict__ w1, const float* __restrict__ b1,
    const float* __restrict__ w2, const float* __restrict__ b2,
    float* __restrict__ assign, int N) {
    __shared__ float s_w1[128 * 64];
    __shared__ float s_w2[64 * 8];
    __shared__ float s_h[32][128];
    __shared__ float s_hid[32][64];
    const int t = threadIdx.x;
    const int n0 = blockIdx.x * 32;
    for (int i = t; i < 128 * 64; i += 256) s_w1[i] = w1[i];
    for (int i = t; i < 512; i += 256) s_w2[i] = w2[i];
    for (int i = t; i < 32 * 32; i += 256) {
        int r = i >> 5, c4 = (i & 31) << 2;
        int gn = n0 + r;
        float4 v = {0.f, 0.f, 0.f, 0.f};
        if (gn < N) v = *(const float4*)(h + (size_t)gn * HH + c4);
        *(float4*)(&s_h[r][c4]) = v;
    }
    __syncthreads();
    for (int o = t; o < 32 * 64; o += 256) {
        int nn = o >> 6, j = o & 63;
        float acc = b1[j];
        for (int k = 0; k < 128; k++) acc = fmaf(s_h[nn][k], s_w1[k * 64 + j], acc);
        s_hid[nn][j] = fmaxf(acc, 0.f);
    }
    __syncthreads();
    int nn = t >> 3, kk = t & 7;
    int gn = n0 + nn;
    float a = b2[kk];
    for (int j = 0; j < 64; j++) a = fmaf(s_hid[nn][j], s_w2[j * 8 + kk], a);
    if (gn < N) a += gum[(size_t)gn * 8 + kk];
    float m = a;
    m = fmaxf(m, __shfl_xor(m, 1));
    m = fmaxf(m, __shfl_xor(m, 2));
    m = fmaxf(m, __shfl_xor(m, 4));
    float e = expf(a - m);
    float s = e;
    s += __shfl_xor(s, 1); s += __shfl_xor(s, 2); s += __shfl_xor(s, 4);
    if (gn < N) assign[(size_t)gn * 8 + kk] = e / s;
}

// ---------------- fused tail: pool + blob + LN + max + clf1 -----------------
__device__ __forceinline__ int lowerb(const int* __restrict__ arr, int n, int val) {
    int lo = 0, hi = n;
    while (lo < hi) {
        int mid = (lo + hi) >> 1;
        if (arr[mid] < val) lo = mid + 1;
        else hi = mid;
    }
    return lo;
}

__global__ __launch_bounds__(1024) void k_tail(
    const float* __restrict__ h, const float* __restrict__ assign,
    const int* __restrict__ batch, const float* __restrict__ bm_w,
    const float* __restrict__ bm_b, const float* __restrict__ ln_g,
    const float* __restrict__ ln_b, const float* __restrict__ clf1_w,
    const float* __restrict__ clf1_b, float* __restrict__ t4,
    float* __restrict__ stats, int N) {
    __shared__ float4 s_num[4][8][32];
    __shared__ float4 s_gm[4][32];
    __shared__ float s_den[4][8];
    __shared__ float s_numf[8][128];
    __shared__ float s_denf[8];
    __shared__ float s_blob[8][128];
    __shared__ float s_cat[256];
    __shared__ float s_r[16][2];
    const int g = blockIdx.x;
    const int t = threadIdx.x;
    const int ns = t >> 8;
    const int k = (t >> 5) & 7;
    const int lane = t & 31;
    const int c4 = lane << 2;
    const int start = lowerb(batch, N, g);
    const int end = lowerb(batch, N, g + 1);

    float4 an = {0.f, 0.f, 0.f, 0.f};
    float4 gm = {0.f, 0.f, 0.f, 0.f};
    float ad = 0.f;
    for (int n = start + ns; n < end; n += 4) {
        float a = assign[(size_t)n * 8 + k];
        const float4 hv = *(const float4*)(h + (size_t)n * HH + c4);
        an.x = fmaf(a, hv.x, an.x);
        an.y = fmaf(a, hv.y, an.y);
        an.z = fmaf(a, hv.z, an.z);
        an.w = fmaf(a, hv.w, an.w);
        if (k == 0) { gm.x += hv.x; gm.y += hv.y; gm.z += hv.z; gm.w += hv.w; }
        ad += a;
    }
    s_num[ns][k][lane] = an;
    if (k == 0) s_gm[ns][lane] = gm;
    if (lane == 0) s_den[ns][k] = ad;
    __syncthreads();
    if (t < 256) {
        float4 a0 = s_num[0][k][lane], a1 = s_num[1][k][lane];
        float4 a2 = s_num[2][k][lane], a3 = s_num[3][k][lane];
        s_numf[k][c4 + 0] = a0.x + a1.x + a2.x + a3.x;
        s_numf[k][c4 + 1] = a0.y + a1.y + a2.y + a3.y;
        s_numf[k][c4 + 2] = a0.z + a1.z + a2.z + a3.z;
        s_numf[k][c4 + 3] = a0.w + a1.w + a2.w + a3.w;
        if (t < 32) {
            float4 g0 = s_gm[0][lane], g1 = s_gm[1][lane];
            float4 g2 = s_gm[2][lane], g3 = s_gm[3][lane];
            int cnt = end - start;
            float inv = 1.f / (float)(cnt > 0 ? cnt : 1);
            s_cat[c4 + 0] = (g0.x + g1.x + g2.x + g3.x) * inv;
            s_cat[c4 + 1] = (g0.y + g1.y + g2.y + g3.y) * inv;
            s_cat[c4 + 2] = (g0.z + g1.z + g2.z + g3.z) * inv;
            s_cat[c4 + 3] = (g0.w + g1.w + g2.w + g3.w) * inv;
        }
        if (t < 8) s_denf[t] = s_den[0][t] + s_den[1][t] + s_den[2][t] + s_den[3][t];
    }
    __syncthreads();

    {
        const int kk = t >> 7;
        const int c = t & 127;
        const float d = 1.f / (s_denf[kk] + 1e-8f);
        float acc = bm_b[c];
        for (int j = 0; j < 128; j++)
            acc = fmaf(s_numf[kk][j] * d, bm_w[j * HH + c], acc);
        float y = fmaxf(acc, 0.f);
        float s = y, q = y * y;
        for (int off = 32; off > 0; off >>= 1) {
            s += __shfl_down(s, off);
            q += __shfl_down(q, off);
        }
        const int wv = t >> 6;
        if ((t & 63) == 0) { s_r[wv][0] = s; s_r[wv][1] = q; }
        __syncthreads();
        float S = s_r[kk * 2][0] + s_r[kk * 2 + 1][0];
        float Q = s_r[kk * 2][1] + s_r[kk * 2 + 1][1];
        float m = S * (1.f / 128.f);
        float var = Q * (1.f / 128.f) - m * m;
        s_blob[kk][c] = (y - m) * rsqrtf(var + 1e-5f) * ln_g[c] + ln_b[c];
    }
    __syncthreads();

    if (t < 128) {
        float m = s_blob[0][t];
#pragma unroll
        for (int kk = 1; kk < 8; kk++) m = fmaxf(m, s_blob[kk][t]);
        s_cat[128 + t] = m;
    }
    __syncthreads();

    if (t < 128) {
        float acc = clf1_b[t];
        for (int j = 0; j < 256; j++) acc = fmaf(s_cat[j], clf1_w[j * HH + t], acc);
        t4[(size_t)g * HH + t] = acc;
        atomAddF(&stats[t], acc);
        atomAddF(&stats[HH + t], acc * acc);
    }
}

__global__ void k_clf2(const float* __restrict__ t4, const float* __restrict__ stats,
                       const float* __restrict__ g_, const float* __restrict__ b_,
                       float invG, const float* __restrict__ w,
                       const float* __restrict__ bias, float* __restrict__ out) {
    int g = blockIdx.x;
    int t = threadIdx.x;  // 128
    __shared__ float s[128];
    float m = stats[t] * invG;
    float var = stats[128 + t] * invG - m * m;
    float sc = g_[t] * rsqrtf(var + 1e-5f);
    float sh = b_[t] - m * sc;
    s[t] = fmaxf(t4[(size_t)g * HH + t] * sc + sh, 0.f);
    __syncthreads();
    if (t < 10) {
        float acc = bias[t];
        for (int j = 0; j < 128; j++) acc = fmaf(s[j], w[j * 10 + t], acc);
        out[(size_t)g * 10 + t] = acc;
    }
}

extern "C" void kernel_launch(void* const* d_in, const int* in_sizes, int n_in,
                              void* d_out, int out_size, void* d_ws, size_t ws_size,
                              hipStream_t stream) {
    const float* x      = (const float*)d_in[0];
    const int*   ei     = (const int*)d_in[1];
    const int*   batch  = (const int*)d_in[2];
    const float* gumbel = (const float*)d_in[3];
    const float* inp_w  = (const float*)d_in[4];
    const float* inp_b  = (const float*)d_in[5];
    const float* elin_w = (const float*)d_in[6];
    const float* elin_b = (const float*)d_in[7];
    const float* mlp1_w = (const float*)d_in[8];
    const float* mlp1_b = (const float*)d_in[9];
    const float* mlpbn_g = (const float*)d_in[10];
    const float* mlpbn_b = (const float*)d_in[11];
    const float* mlp2_w = (const float*)d_in[12];
    const float* mlp2_b = (const float*)d_in[13];
    const float* bn_g   = (const float*)d_in[14];
    const float* bn_b   = (const float*)d_in[15];
    const float* bh1_w  = (const float*)d_in[16];
    const float* bh1_b  = (const float*)d_in[17];
    const float* bh2_w  = (const float*)d_in[18];
    const float* bh2_b  = (const float*)d_in[19];
    const float* bm_w   = (const float*)d_in[20];
    const float* bm_b   = (const float*)d_in[21];
    const float* ln_g   = (const float*)d_in[22];
    const float* ln_b   = (const float*)d_in[23];
    const float* clf1_w = (const float*)d_in[24];
    const float* clf1_b = (const float*)d_in[25];
    const float* clfbn_g = (const float*)d_in[26];
    const float* clfbn_b = (const float*)d_in[27];
    const float* clf2_w = (const float*)d_in[28];
    const float* clf2_b = (const float*)d_in[29];
    float* out = (float*)d_out;

    const int N = in_sizes[0] / 64;
    const int E = in_sizes[1] / 2;
    const int G = out_size / 10;

    float* ws = (float*)d_ws;
    float* A      = ws;                                  // z (u16 hi/lo) / h f32
    float* B      = A + (size_t)N * HH;                  // t2b (u16) / t2 f32
    float* C      = B + (size_t)N * HH;                  // act0+hb (u16) / t1 f32
    float* assign = C + (size_t)N * HH;                  // N*8
    float* t4     = assign + (size_t)N * 8;              // G*128
    float* statsA = t4 + (size_t)G * HH;                 // 7*256
    u16* Whi = (u16*)(statsA + 7 * 256);                 // WTOT
    u16* Wlo = Whi + WTOT;                               // WTOT
    int* rowptr = (int*)(Wlo + WTOT);                    // N+1
    int* cursor = rowptr + (N + 1);                      // N (also deg)
    int* colidx = cursor + N;                            // E
    int* bsum   = colidx + E;                            // 256
    int* boff   = bsum + 256;                            // 256
    // aliases:
    u16* zhi  = (u16*)A;
    u16* zlo  = zhi + (size_t)N * HH;
    float* h  = A;
    u16* t2b  = (u16*)B;
    float* t2f = B;
    u16* hb   = (u16*)C;   // act0 / per-layer bf16 h
    float* t1 = C;

    const dim3 B256(256), B128(128), B512(512), B1024(1024);
    const int ntiles = (N + 127) / 128;
    const int gg = ntiles < 512 ? ntiles : 512;
    const int nch = (N + 255) / 256;
    const int e4 = (E + 4 * 256 - 1) / (4 * 256);
    const float invN = 1.f / (float)N;
    const float invG = 1.f / (float)G;

    // weight prep + CSR build + stats clear
    k_prep<<<7, B256, 0, stream>>>(inp_w, mlp1_w, mlp2_w, Whi, Wlo);
    hipMemsetAsync(cursor, 0, (size_t)N * sizeof(int), stream);
    hipMemsetAsync(statsA, 0, 7 * 256 * sizeof(float), stream);
    k_hist<<<e4, B256, 0, stream>>>(ei, cursor, E);
    k_bsum<<<nch, B256, 0, stream>>>(cursor, bsum, N);
    k_scan1<<<1, B256, 0, stream>>>(bsum, boff, rowptr + N, nch);
    k_scan2<<<nch, B256, 0, stream>>>(cursor, boff, rowptr, cursor, N);
    k_fill<<<e4, B256, 0, stream>>>(ei, cursor, colidx, E);

    // hb = bf16(x @ inp_w + inp_b)
    k_mgemm<64, 0, false, false, true><<<gg, B512, 0, stream>>>(
        x, nullptr, nullptr, Whi, Wlo, inp_b, nullptr, nullptr, nullptr, 0.f,
        nullptr, hb, nullptr, N, ntiles);

    for (int l = 0; l < 3; l++) {
        float* sa = statsA + (size_t)(2 * l) * 256;
        float* sb = sa + 256;
        k_gather<<<(N + 1) / 2, B256, 0, stream>>>(hb, rowptr, colidx,
                                                   elin_w + l * HH, elin_b + l * HH,
                                                   zhi, zlo, N);
        // t1 = z @ W1 + b1 (stats -> sa)
        k_mgemm<128, 2, true, true, false><<<gg, B512, 0, stream>>>(
            nullptr, zhi, zlo, Whi + 8192 + (size_t)l * 16384,
            Wlo + 8192 + (size_t)l * 16384, mlp1_b + l * HH,
            nullptr, nullptr, nullptr, 0.f, t1, nullptr, sa, N, ntiles);
        // t2 = relu(bn(t1)) @ W2 + b2 ; bf16 out for l<2, f32 for l==2
        if (l < 2) {
            k_mgemm<128, 1, true, false, true><<<gg, B512, 0, stream>>>(
                t1, nullptr, nullptr, Whi + 8192 + (size_t)(3 + l) * 16384,
                Wlo + 8192 + (size_t)(3 + l) * 16384, mlp2_b + l * HH,
                sa, mlpbn_g + l * HH, mlpbn_b + l * HH, invN,
                nullptr, t2b, sb, N, ntiles);
            // hb = bf16(relu(bn(t2b)))
            k_bnrelu_bf<<<(N * 32 + 255) / 256, B256, 0, stream>>>(
                t2b, sb, bn_g + l * HH, bn_b + l * HH, invN, hb, N * 32);
        } else {
            k_mgemm<128, 1, true, true, false><<<gg, B512, 0, stream>>>(
                t1, nullptr, nullptr, Whi + 8192 + (size_t)(3 + l) * 16384,
                Wlo + 8192 + (size_t)(3 + l) * 16384, mlp2_b + l * HH,
                sa, mlpbn_g + l * HH, mlpbn_b + l * HH, invN,
                t2f, nullptr, sb, N, ntiles);
            k_bnrelu<<<(N * 32 + 255) / 256, B256, 0, stream>>>(
                t2f, sb, bn_g + l * HH, bn_b + l * HH, invN, h, N * 32);
        }
    }

    k_assign<<<(N + 31) / 32, B256, 0, stream>>>(h, gumbel, bh1_w, bh1_b, bh2_w, bh2_b, assign, N);
    float* sc_ = statsA + 6 * 256;
    k_tail<<<G, B1024, 0, stream>>>(h, assign, batch, bm_w, bm_b, ln_g, ln_b,
                                    clf1_w, clf1_b, t4, sc_, N);
    k_clf2<<<G, B128, 0, stream>>>(t4, sc_, clfbn_g, clfbn_b, invG, clf2_w, clf2_b, out);
}

// Round 15
// 501.864 us; speedup vs baseline: 1.5321x; 1.5321x over previous
//
#include <hip/hip_runtime.h>
#include <hip/hip_bf16.h>

// ---------------------------------------------------------------------------
// SoftBlobGIN round 15: recombine measured-best pieces — R13 mgemm (B-LDS
// staged once, A-direct), pure gather (R11 form) + cheap bf16 bnrelu, k_tail.
// ---------------------------------------------------------------------------

#define HH 128
typedef unsigned short u16;
typedef unsigned int u32;
typedef __attribute__((ext_vector_type(8))) short bf16x8;
typedef __attribute__((ext_vector_type(4))) float f32x4;

__device__ __forceinline__ void atomAddF(float* p, float v) { unsafeAtomicAdd(p, v); }

__device__ __forceinline__ u16 f2bf(float f) {          // RNE f32->bf16
    u32 u = __float_as_uint(f);
    u += 0x7fffu + ((u >> 16) & 1u);
    return (u16)(u >> 16);
}
__device__ __forceinline__ float bf2f_lo(u32 u) { return __uint_as_float(u << 16); }
__device__ __forceinline__ float bf2f_hi(u32 u) { return __uint_as_float(u & 0xffff0000u); }
__device__ __forceinline__ void split2(float v, u16& hi, u16& lo) {
    u16 h_ = f2bf(v);
    float hf = __uint_as_float(((u32)h_) << 16);
    hi = h_;
    lo = f2bf(v - hf);
}
__device__ __forceinline__ u32 swz(u32 row, u32 kByte, u32 strideB) {
    return (row * strideB + kByte) ^ ((row & 7u) << 4);
}

#define WTOT (8192 + 6 * 16384)

// ---------------- weight prep ----------------
__global__ void k_prep(const float* __restrict__ inp_w, const float* __restrict__ m1,
                       const float* __restrict__ m2, u16* __restrict__ Whi,
                       u16* __restrict__ Wlo) {
    int b = blockIdx.x;  // 0..6
    int t = threadIdx.x; // 256
    if (b == 0) {
        for (int idx = t; idx < 128 * 64; idx += 256) {
            int c = idx >> 6, k = idx & 63;
            u16 hi, lo;
            split2(inp_w[k * 128 + c], hi, lo);
            Whi[idx] = hi; Wlo[idx] = lo;
        }
    } else {
        const float* W = (b <= 3) ? m1 + (size_t)(b - 1) * 16384
                                  : m2 + (size_t)(b - 4) * 16384;
        u16* dh = Whi + 8192 + (size_t)(b - 1) * 16384;
        u16* dl = Wlo + 8192 + (size_t)(b - 1) * 16384;
        for (int idx = t; idx < 16384; idx += 256) {
            int c = idx >> 7, k = idx & 127;
            u16 hi, lo;
            split2(W[k * 128 + c], hi, lo);
            dh[idx] = hi; dl[idx] = lo;
        }
    }
}

// ---------------- CSR build (4 edges/thread) ----------------
__global__ void k_hist(const int* __restrict__ ei, int* __restrict__ deg, int E) {
    int i4 = blockIdx.x * 256 + threadIdx.x;
    int e0 = i4 * 4;
    if (e0 + 3 < E) {
        int4 d = *(const int4*)(ei + E + e0);
        atomicAdd(&deg[d.x], 1);
        atomicAdd(&deg[d.y], 1);
        atomicAdd(&deg[d.z], 1);
        atomicAdd(&deg[d.w], 1);
    } else {
        for (int e = e0; e < E; e++) atomicAdd(&deg[ei[E + e]], 1);
    }
}

__global__ void k_bsum(const int* __restrict__ deg, int* __restrict__ bsum, int N) {
    int t = threadIdx.x;
    int i = blockIdx.x * 256 + t;
    int v = (i < N) ? deg[i] : 0;
    for (int o = 32; o; o >>= 1) v += __shfl_down(v, o);
    __shared__ int ws_[4];
    if ((t & 63) == 0) ws_[t >> 6] = v;
    __syncthreads();
    if (t == 0) bsum[blockIdx.x] = ws_[0] + ws_[1] + ws_[2] + ws_[3];
}

__global__ void k_scan1(const int* __restrict__ bsum, int* __restrict__ boff,
                        int* __restrict__ rowptrN, int nch) {
    int t = threadIdx.x;  // 256
    int v = (t < nch) ? bsum[t] : 0;
    int l = t & 63, w = t >> 6;
    int sv = v;
    for (int o = 1; o < 64; o <<= 1) { int u = __shfl_up(sv, o); if (l >= o) sv += u; }
    __shared__ int wsum[4];
    if (l == 63) wsum[w] = sv;
    __syncthreads();
    int add = 0;
    for (int j = 0; j < w; j++) add += wsum[j];
    if (t < nch) boff[t] = sv - v + add;
    if (t == nch - 1) *rowptrN = sv + add;
}

__global__ void k_scan2(const int* __restrict__ deg, const int* __restrict__ boff,
                        int* __restrict__ rowptr, int* __restrict__ cursor, int N) {
    int b = blockIdx.x, t = threadIdx.x, i = b * 256 + t;
    int v = (i < N) ? deg[i] : 0;
    int l = t & 63, w = t >> 6;
    int sv = v;
    for (int o = 1; o < 64; o <<= 1) { int u = __shfl_up(sv, o); if (l >= o) sv += u; }
    __shared__ int wsum[4];
    if (l == 63) wsum[w] = sv;
    __syncthreads();
    int add = boff[b];
    for (int j = 0; j < w; j++) add += wsum[j];
    if (i < N) { int e = sv - v + add; rowptr[i] = e; cursor[i] = e; }
}

__global__ void k_fill(const int* __restrict__ ei, int* __restrict__ cursor,
                       int* __restrict__ col, int E) {
    int i4 = blockIdx.x * 256 + threadIdx.x;
    int e0 = i4 * 4;
    if (e0 + 3 < E) {
        int4 s = *(const int4*)(ei + e0);
        int4 d = *(const int4*)(ei + E + e0);
        int p0 = atomicAdd(&cursor[d.x], 1);
        int p1 = atomicAdd(&cursor[d.y], 1);
        int p2 = atomicAdd(&cursor[d.z], 1);
        int p3 = atomicAdd(&cursor[d.w], 1);
        col[p0] = s.x;
        col[p1] = s.y;
        col[p2] = s.z;
        col[p3] = s.w;
    } else {
        for (int e = e0; e < E; e++) {
            int pos = atomicAdd(&cursor[ei[E + e]], 1);
            col[pos] = ei[e];
        }
    }
}

// ---------------- MFMA GEMM: A direct from global; B staged in LDS ----------
// MODE 0: f32 input | MODE 1: f32 input + bn-relu | MODE 2: bf16 hi/lo input
template <int KD, int MODE, bool STATS, bool FOUT, bool BOUT>
__global__ __launch_bounds__(512) void k_mgemm(
    const float* __restrict__ inf, const u16* __restrict__ inhi,
    const u16* __restrict__ inlo, const u16* __restrict__ Whi,
    const u16* __restrict__ Wlo, const float* __restrict__ bias,
    const float* __restrict__ statsIn, const float* __restrict__ gamma,
    const float* __restrict__ beta, float invN,
    float* __restrict__ out, u16* __restrict__ outb,
    float* __restrict__ statsOut, int Nrows, int ntiles) {
    __shared__ u16 s_Bhi[128 * KD];
    __shared__ u16 s_Blo[128 * KD];
    __shared__ float s_red[2][8][128];
    __shared__ float s_sc[128], s_sh[128];
    const int t = threadIdx.x;
    constexpr u32 STR = KD * 2;
    constexpr int KCB = KD / 8;
    constexpr int NB = (128 * KCB) / 512;
    constexpr int NF = KD / 32;

#pragma unroll
    for (int i = 0; i < NB; i++) {
        int idx = i * 512 + t;
        int c = idx / KCB, kc = idx % KCB;
        u32 off = swz(c, kc * 16, STR);
        *(uint4*)((char*)s_Bhi + off) = *(const uint4*)(Whi + (size_t)c * KD + kc * 8);
        *(uint4*)((char*)s_Blo + off) = *(const uint4*)(Wlo + (size_t)c * KD + kc * 8);
    }
    if (MODE == 1 && t < 128) {
        float m = statsIn[t] * invN;
        float var = statsIn[128 + t] * invN - m * m;
        float s = gamma[t] * rsqrtf(var + 1e-5f);
        s_sc[t] = s;
        s_sh[t] = beta[t] - m * s;
    }
    __syncthreads();

    const int l = t & 63, w = t >> 6;
    const int c0 = l & 15;
    const int ksub = (l >> 4) * 8;
    const u32 kOffB = (u32)(l >> 4) * 16u;

    for (int tile = blockIdx.x; tile < ntiles; tile += gridDim.x) {
        const int row = tile * 128 + w * 16 + c0;
        const bool rv = row < Nrows;

        bf16x8 ah[NF], al[NF];
        if (MODE == 2) {
#pragma unroll
            for (int kk = 0; kk < NF; kk++) {
                int k0 = kk * 32 + ksub;
                if (rv) {
                    ah[kk] = *(const bf16x8*)(inhi + (size_t)row * KD + k0);
                    al[kk] = *(const bf16x8*)(inlo + (size_t)row * KD + k0);
                } else {
                    uint4 z = {0, 0, 0, 0};
                    ah[kk] = *(bf16x8*)&z;
                    al[kk] = *(bf16x8*)&z;
                }
            }
        } else {
#pragma unroll
            for (int kk = 0; kk < NF; kk++) {
                int k0 = kk * 32 + ksub;
                float4 v0 = {0.f, 0.f, 0.f, 0.f}, v1 = {0.f, 0.f, 0.f, 0.f};
                if (rv) {
                    v0 = *(const float4*)(inf + (size_t)row * KD + k0);
                    v1 = *(const float4*)(inf + (size_t)row * KD + k0 + 4);
                }
                float vv[8] = {v0.x, v0.y, v0.z, v0.w, v1.x, v1.y, v1.z, v1.w};
                uint4 uh, ul;
                u32* ph = (u32*)&uh;
                u32* pl = (u32*)&ul;
#pragma unroll
                for (int p = 0; p < 4; p++) {
                    float a0 = vv[2 * p], a1 = vv[2 * p + 1];
                    if (MODE == 1) {
                        a0 = fmaxf(a0 * s_sc[k0 + 2 * p] + s_sh[k0 + 2 * p], 0.f);
                        a1 = fmaxf(a1 * s_sc[k0 + 2 * p + 1] + s_sh[k0 + 2 * p + 1], 0.f);
                    }
                    u16 h0, l0, h1, l1;
                    split2(a0, h0, l0);
                    split2(a1, h1, l1);
                    ph[p] = (u32)h0 | ((u32)h1 << 16);
                    pl[p] = (u32)l0 | ((u32)l1 << 16);
                }
                ah[kk] = *(bf16x8*)&uh;
                al[kk] = *(bf16x8*)&ul;
            }
        }

        f32x4 acc[8];
#pragma unroll
        for (int n = 0; n < 8; n++) acc[n] = (f32x4){0.f, 0.f, 0.f, 0.f};
#pragma unroll
        for (int kk = 0; kk < NF; kk++) {
            u32 kb = kk * 64 + kOffB;
#pragma unroll
            for (int n = 0; n < 8; n++) {
                u32 ob = swz(n * 16 + c0, kb, STR);
                bf16x8 bh = *(const bf16x8*)((char*)s_Bhi + ob);
                bf16x8 bl = *(const bf16x8*)((char*)s_Blo + ob);
                acc[n] = __builtin_amdgcn_mfma_f32_16x16x32_bf16(ah[kk], bh, acc[n], 0, 0, 0);
                acc[n] = __builtin_amdgcn_mfma_f32_16x16x32_bf16(al[kk], bh, acc[n], 0, 0, 0);
                acc[n] = __builtin_amdgcn_mfma_f32_16x16x32_bf16(ah[kk], bl, acc[n], 0, 0, 0);
            }
        }

        const int rbase = tile * 128 + w * 16 + ((l >> 4) << 2);
#pragma unroll
        for (int n = 0; n < 8; n++) {
            const int colc = n * 16 + c0;
            const float bv = bias[colc];
            float s = 0.f, q = 0.f;
#pragma unroll
            for (int j = 0; j < 4; j++) {
                int gr = rbase + j;
                if (gr < Nrows) {
                    float v = acc[n][j] + bv;
                    if (FOUT) out[(size_t)gr * HH + colc] = v;
                    if (BOUT) outb[(size_t)gr * HH + colc] = f2bf(v);
                    s += v;
                    q += v * v;
                }
            }
            if (STATS) {
                s += __shfl_xor(s, 16); s += __shfl_xor(s, 32);
                q += __shfl_xor(q, 16); q += __shfl_xor(q, 32);
                if (l < 16) {
                    s_red[0][w][n * 16 + l] = s;
                    s_red[1][w][n * 16 + l] = q;
                }
            }
        }
        if (STATS) {
            __syncthreads();
            if (t < 128) {
                float S = 0.f, Q = 0.f;
#pragma unroll
                for (int ww = 0; ww < 8; ww++) { S += s_red[0][ww][t]; Q += s_red[1][ww][t]; }
                atomAddF(&statsOut[t], S);
                atomAddF(&statsOut[HH + t], Q);
            }
            __syncthreads();
        }
    }
}

// ---------------- gather: 2 waves/node, 8-deep unroll (pure form) -----------
__global__ __launch_bounds__(256) void k_gather(
    const u16* __restrict__ hb,
    const int* __restrict__ rowptr, const int* __restrict__ col,
    const float* __restrict__ ew, const float* __restrict__ eb,
    u16* __restrict__ zhi, u16* __restrict__ zlo, int N) {
    __shared__ float2 s_part[2][64];
    const int wv = threadIdx.x >> 6;
    const int lane = threadIdx.x & 63;
    const int node = blockIdx.x * 2 + (wv >> 1);
    const int hf = wv & 1;
    const int c2 = lane * 2;
    float2 acc = {0.f, 0.f};
    const bool valid = node < N;
    float2 ee = {0.f, 0.f};
    if (valid) {
        ee.x = ew[c2] + eb[c2];
        ee.y = ew[c2 + 1] + eb[c2 + 1];
        const int s = rowptr[node], eend = rowptr[node + 1];
        int e = s + hf;
        for (; e + 14 < eend; e += 16) {
            int s0 = col[e], s1 = col[e + 2], s2 = col[e + 4], s3 = col[e + 6];
            int s4 = col[e + 8], s5 = col[e + 10], s6 = col[e + 12], s7 = col[e + 14];
            u32 u0 = *(const u32*)(hb + (size_t)s0 * HH + c2);
            u32 u1 = *(const u32*)(hb + (size_t)s1 * HH + c2);
            u32 u2 = *(const u32*)(hb + (size_t)s2 * HH + c2);
            u32 u3 = *(const u32*)(hb + (size_t)s3 * HH + c2);
            u32 u4 = *(const u32*)(hb + (size_t)s4 * HH + c2);
            u32 u5 = *(const u32*)(hb + (size_t)s5 * HH + c2);
            u32 u6 = *(const u32*)(hb + (size_t)s6 * HH + c2);
            u32 u7 = *(const u32*)(hb + (size_t)s7 * HH + c2);
            acc.x += fmaxf(bf2f_lo(u0) + ee.x, 0.f) + fmaxf(bf2f_lo(u1) + ee.x, 0.f) +
                     fmaxf(bf2f_lo(u2) + ee.x, 0.f) + fmaxf(bf2f_lo(u3) + ee.x, 0.f) +
                     fmaxf(bf2f_lo(u4) + ee.x, 0.f) + fmaxf(bf2f_lo(u5) + ee.x, 0.f) +
                     fmaxf(bf2f_lo(u6) + ee.x, 0.f) + fmaxf(bf2f_lo(u7) + ee.x, 0.f);
            acc.y += fmaxf(bf2f_hi(u0) + ee.y, 0.f) + fmaxf(bf2f_hi(u1) + ee.y, 0.f) +
                     fmaxf(bf2f_hi(u2) + ee.y, 0.f) + fmaxf(bf2f_hi(u3) + ee.y, 0.f) +
                     fmaxf(bf2f_hi(u4) + ee.y, 0.f) + fmaxf(bf2f_hi(u5) + ee.y, 0.f) +
                     fmaxf(bf2f_hi(u6) + ee.y, 0.f) + fmaxf(bf2f_hi(u7) + ee.y, 0.f);
        }
        for (; e + 6 < eend; e += 8) {
            int s0 = col[e], s1 = col[e + 2], s2 = col[e + 4], s3 = col[e + 6];
            u32 u0 = *(const u32*)(hb + (size_t)s0 * HH + c2);
            u32 u1 = *(const u32*)(hb + (size_t)s1 * HH + c2);
            u32 u2 = *(const u32*)(hb + (size_t)s2 * HH + c2);
            u32 u3 = *(const u32*)(hb + (size_t)s3 * HH + c2);
            acc.x += fmaxf(bf2f_lo(u0) + ee.x, 0.f) + fmaxf(bf2f_lo(u1) + ee.x, 0.f) +
                     fmaxf(bf2f_lo(u2) + ee.x, 0.f) + fmaxf(bf2f_lo(u3) + ee.x, 0.f);
            acc.y += fmaxf(bf2f_hi(u0) + ee.y, 0.f) + fmaxf(bf2f_hi(u1) + ee.y, 0.f) +
                     fmaxf(bf2f_hi(u2) + ee.y, 0.f) + fmaxf(bf2f_hi(u3) + ee.y, 0.f);
        }
        for (; e < eend; e += 2) {
            u32 u0 = *(const u32*)(hb + (size_t)col[e] * HH + c2);
            acc.x += fmaxf(bf2f_lo(u0) + ee.x, 0.f);
            acc.y += fmaxf(bf2f_hi(u0) + ee.y, 0.f);
        }
    }
    if (hf) s_part[wv >> 1][lane] = acc;
    __syncthreads();
    if (!hf && valid) {
        float2 p = s_part[wv >> 1][lane];
        u32 un = *(const u32*)(hb + (size_t)node * HH + c2);
        float zx = bf2f_lo(un) + acc.x + p.x;
        float zy = bf2f_hi(un) + acc.y + p.y;
        u16 h0, h1, l0, l1;
        split2(zx, h0, l0);
        split2(zy, h1, l1);
        *(u32*)(zhi + (size_t)node * HH + c2) = (u32)h0 | ((u32)h1 << 16);
        *(u32*)(zlo + (size_t)node * HH + c2) = (u32)l0 | ((u32)l1 << 16);
    }
}

// ---------------- bnrelu bf16->bf16 (layers 0,1) ----------------
__global__ void k_bnrelu_bf(const u16* __restrict__ tb, const float* __restrict__ stats,
                            const float* __restrict__ g, const float* __restrict__ b,
                            float invN, u16* __restrict__ hb, int total4) {
    int i = blockIdx.x * 256 + threadIdx.x;
    if (i >= total4) return;
    int c4 = (i & 31) << 2;
    float sc[4], sh[4];
#pragma unroll
    for (int j = 0; j < 4; j++) {
        float m = stats[c4 + j] * invN;
        float var = stats[128 + c4 + j] * invN - m * m;
        float s = g[c4 + j] * rsqrtf(var + 1e-5f);
        sc[j] = s;
        sh[j] = b[c4 + j] - m * s;
    }
    uint2 v = *(const uint2*)(tb + (size_t)i * 4);
    float o0 = fmaxf(bf2f_lo(v.x) * sc[0] + sh[0], 0.f);
    float o1 = fmaxf(bf2f_hi(v.x) * sc[1] + sh[1], 0.f);
    float o2 = fmaxf(bf2f_lo(v.y) * sc[2] + sh[2], 0.f);
    float o3 = fmaxf(bf2f_hi(v.y) * sc[3] + sh[3], 0.f);
    uint2 p = {(u32)f2bf(o0) | ((u32)f2bf(o1) << 16),
               (u32)f2bf(o2) | ((u32)f2bf(o3) << 16)};
    *(uint2*)(hb + (size_t)i * 4) = p;
}

// ---------------- bnrelu f32 (final layer) ----------------
__global__ void k_bnrelu(const float* __restrict__ t, const float* __restrict__ stats,
                         const float* __restrict__ g, const float* __restrict__ b,
                         float invN, float* __restrict__ h, int total4) {
    int i = blockIdx.x * 256 + threadIdx.x;
    if (i >= total4) return;
    int c4 = (i & 31) << 2;
    float sc[4], sh[4];
#pragma unroll
    for (int j = 0; j < 4; j++) {
        float m = stats[c4 + j] * invN;
        float var = stats[128 + c4 + j] * invN - m * m;
        float s = g[c4 + j] * rsqrtf(var + 1e-5f);
        sc[j] = s;
        sh[j] = b[c4 + j] - m * s;
    }
    float4 v = *(const float4*)(t + (size_t)i * 4);
    float4 o;
    o.x = fmaxf(v.x * sc[0] + sh[0], 0.f);
    o.y = fmaxf(v.y * sc[1] + sh[1], 0.f);
    o.z = fmaxf(v.z * sc[2] + sh[2], 0.f);
    o.w = fmaxf(v.w * sc[3] + sh[3], 0.f);
    *(float4*)(h + (size_t)i * 4) = o;
}

// ---------------- assign ----------------
__global__ __launch_bounds__(256) void k_assign(
    const float* __restrict__ h, const float* __restrict__ gum,
    const float* __restrict__ w1, const float* __restrict__ b1,
    const float* __restrict__ w2, const float* __restrict__ b2,
    float* __restrict__ assign, int N) {
    __shared__ float s_w1[128 * 64];
    __shared__ float s_w2[64 * 8];
    __shared__ float s_h[32][128];
    __shared__ float s_hid[32][64];
    const int t = threadIdx.x;
    const int n0 = blockIdx.x * 32;
    for (int i = t; i < 128 * 64; i += 256) s_w1[i] = w1[i];
    for (int i = t; i < 512; i += 256) s_w2[i] = w2[i];
    for (int i = t; i < 32 * 32; i += 256) {
        int r = i >> 5, c4 = (i & 31) << 2;
        int gn = n0 + r;
        float4 v = {0.f, 0.f, 0.f, 0.f};
        if (gn < N) v = *(const float4*)(h + (size_t)gn * HH + c4);
        *(float4*)(&s_h[r][c4]) = v;
    }
    __syncthreads();
    for (int o = t; o < 32 * 64; o += 256) {
        int nn = o >> 6, j = o & 63;
        float acc = b1[j];
        for (int k = 0; k < 128; k++) acc = fmaf(s_h[nn][k], s_w1[k * 64 + j], acc);
        s_hid[nn][j] = fmaxf(acc, 0.f);
    }
    __syncthreads();
    int nn = t >> 3, kk = t & 7;
    int gn = n0 + nn;
    float a = b2[kk];
    for (int j = 0; j < 64; j++) a = fmaf(s_hid[nn][j], s_w2[j * 8 + kk], a);
    if (gn < N) a += gum[(size_t)gn * 8 + kk];
    float m = a;
    m = fmaxf(m, __shfl_xor(m, 1));
    m = fmaxf(m, __shfl_xor(m, 2));
    m = fmaxf(m, __shfl_xor(m, 4));
    float e = expf(a - m);
    float s = e;
    s += __shfl_xor(s, 1); s += __shfl_xor(s, 2); s += __shfl_xor(s, 4);
    if (gn < N) assign[(size_t)gn * 8 + kk] = e / s;
}

// ---------------- fused tail: pool + blob + LN + max + clf1 -----------------
__device__ __forceinline__ int lowerb(const int* __restrict__ arr, int n, int val) {
    int lo = 0, hi = n;
    while (lo < hi) {
        int mid = (lo + hi) >> 1;
        if (arr[mid] < val) lo = mid + 1;
        else hi = mid;
    }
    return lo;
}

__global__ __launch_bounds__(1024) void k_tail(
    const float* __restrict__ h, const float* __restrict__ assign,
    const int* __restrict__ batch, const float* __restrict__ bm_w,
    const float* __restrict__ bm_b, const float* __restrict__ ln_g,
    const float* __restrict__ ln_b, const float* __restrict__ clf1_w,
    const float* __restrict__ clf1_b, float* __restrict__ t4,
    float* __restrict__ stats, int N) {
    __shared__ float4 s_num[4][8][32];
    __shared__ float4 s_gm[4][32];
    __shared__ float s_den[4][8];
    __shared__ float s_numf[8][128];
    __shared__ float s_denf[8];
    __shared__ float s_blob[8][128];
    __shared__ float s_cat[256];
    __shared__ float s_r[16][2];
    const int g = blockIdx.x;
    const int t = threadIdx.x;
    const int ns = t >> 8;
    const int k = (t >> 5) & 7;
    const int lane = t & 31;
    const int c4 = lane << 2;
    const int start = lowerb(batch, N, g);
    const int end = lowerb(batch, N, g + 1);

    float4 an = {0.f, 0.f, 0.f, 0.f};
    float4 gm = {0.f, 0.f, 0.f, 0.f};
    float ad = 0.f;
    for (int n = start + ns; n < end; n += 4) {
        float a = assign[(size_t)n * 8 + k];
        const float4 hv = *(const float4*)(h + (size_t)n * HH + c4);
        an.x = fmaf(a, hv.x, an.x);
        an.y = fmaf(a, hv.y, an.y);
        an.z = fmaf(a, hv.z, an.z);
        an.w = fmaf(a, hv.w, an.w);
        if (k == 0) { gm.x += hv.x; gm.y += hv.y; gm.z += hv.z; gm.w += hv.w; }
        ad += a;
    }
    s_num[ns][k][lane] = an;
    if (k == 0) s_gm[ns][lane] = gm;
    if (lane == 0) s_den[ns][k] = ad;
    __syncthreads();
    if (t < 256) {
        float4 a0 = s_num[0][k][lane], a1 = s_num[1][k][lane];
        float4 a2 = s_num[2][k][lane], a3 = s_num[3][k][lane];
        s_numf[k][c4 + 0] = a0.x + a1.x + a2.x + a3.x;
        s_numf[k][c4 + 1] = a0.y + a1.y + a2.y + a3.y;
        s_numf[k][c4 + 2] = a0.z + a1.z + a2.z + a3.z;
        s_numf[k][c4 + 3] = a0.w + a1.w + a2.w + a3.w;
        if (t < 32) {
            float4 g0 = s_gm[0][lane], g1 = s_gm[1][lane];
            float4 g2 = s_gm[2][lane], g3 = s_gm[3][lane];
            int cnt = end - start;
            float inv = 1.f / (float)(cnt > 0 ? cnt : 1);
            s_cat[c4 + 0] = (g0.x + g1.x + g2.x + g3.x) * inv;
            s_cat[c4 + 1] = (g0.y + g1.y + g2.y + g3.y) * inv;
            s_cat[c4 + 2] = (g0.z + g1.z + g2.z + g3.z) * inv;
            s_cat[c4 + 3] = (g0.w + g1.w + g2.w + g3.w) * inv;
        }
        if (t < 8) s_denf[t] = s_den[0][t] + s_den[1][t] + s_den[2][t] + s_den[3][t];
    }
    __syncthreads();

    {
        const int kk = t >> 7;
        const int c = t & 127;
        const float d = 1.f / (s_denf[kk] + 1e-8f);
        float acc = bm_b[c];
        for (int j = 0; j < 128; j++)
            acc = fmaf(s_numf[kk][j] * d, bm_w[j * HH + c], acc);
        float y = fmaxf(acc, 0.f);
        float s = y, q = y * y;
        for (int off = 32; off > 0; off >>= 1) {
            s += __shfl_down(s, off);
            q += __shfl_down(q, off);
        }
        const int wv = t >> 6;
        if ((t & 63) == 0) { s_r[wv][0] = s; s_r[wv][1] = q; }
        __syncthreads();
        float S = s_r[kk * 2][0] + s_r[kk * 2 + 1][0];
        float Q = s_r[kk * 2][1] + s_r[kk * 2 + 1][1];
        float m = S * (1.f / 128.f);
        float var = Q * (1.f / 128.f) - m * m;
        s_blob[kk][c] = (y - m) * rsqrtf(var + 1e-5f) * ln_g[c] + ln_b[c];
    }
    __syncthreads();

    if (t < 128) {
        float m = s_blob[0][t];
#pragma unroll
        for (int kk = 1; kk < 8; kk++) m = fmaxf(m, s_blob[kk][t]);
        s_cat[128 + t] = m;
    }
    __syncthreads();

    if (t < 128) {
        float acc = clf1_b[t];
        for (int j = 0; j < 256; j++) acc = fmaf(s_cat[j], clf1_w[j * HH + t], acc);
        t4[(size_t)g * HH + t] = acc;
        atomAddF(&stats[t], acc);
        atomAddF(&stats[HH + t], acc * acc);
    }
}

__global__ void k_clf2(const float* __restrict__ t4, const float* __restrict__ stats,
                       const float* __restrict__ g_, const float* __restrict__ b_,
                       float invG, const float* __restrict__ w,
                       const float* __restrict__ bias, float* __restrict__ out) {
    int g = blockIdx.x;
    int t = threadIdx.x;  // 128
    __shared__ float s[128];
    float m = stats[t] * invG;
    float var = stats[128 + t] * invG - m * m;
    float sc = g_[t] * rsqrtf(var + 1e-5f);
    float sh = b_[t] - m * sc;
    s[t] = fmaxf(t4[(size_t)g * HH + t] * sc + sh, 0.f);
    __syncthreads();
    if (t < 10) {
        float acc = bias[t];
        for (int j = 0; j < 128; j++) acc = fmaf(s[j], w[j * 10 + t], acc);
        out[(size_t)g * 10 + t] = acc;
    }
}

extern "C" void kernel_launch(void* const* d_in, const int* in_sizes, int n_in,
                              void* d_out, int out_size, void* d_ws, size_t ws_size,
                              hipStream_t stream) {
    const float* x      = (const float*)d_in[0];
    const int*   ei     = (const int*)d_in[1];
    const int*   batch  = (const int*)d_in[2];
    const float* gumbel = (const float*)d_in[3];
    const float* inp_w  = (const float*)d_in[4];
    const float* inp_b  = (const float*)d_in[5];
    const float* elin_w = (const float*)d_in[6];
    const float* elin_b = (const float*)d_in[7];
    const float* mlp1_w = (const float*)d_in[8];
    const float* mlp1_b = (const float*)d_in[9];
    const float* mlpbn_g = (const float*)d_in[10];
    const float* mlpbn_b = (const float*)d_in[11];
    const float* mlp2_w = (const float*)d_in[12];
    const float* mlp2_b = (const float*)d_in[13];
    const float* bn_g   = (const float*)d_in[14];
    const float* bn_b   = (const float*)d_in[15];
    const float* bh1_w  = (const float*)d_in[16];
    const float* bh1_b  = (const float*)d_in[17];
    const float* bh2_w  = (const float*)d_in[18];
    const float* bh2_b  = (const float*)d_in[19];
    const float* bm_w   = (const float*)d_in[20];
    const float* bm_b   = (const float*)d_in[21];
    const float* ln_g   = (const float*)d_in[22];
    const float* ln_b   = (const float*)d_in[23];
    const float* clf1_w = (const float*)d_in[24];
    const float* clf1_b = (const float*)d_in[25];
    const float* clfbn_g = (const float*)d_in[26];
    const float* clfbn_b = (const float*)d_in[27];
    const float* clf2_w = (const float*)d_in[28];
    const float* clf2_b = (const float*)d_in[29];
    float* out = (float*)d_out;

    const int N = in_sizes[0] / 64;
    const int E = in_sizes[1] / 2;
    const int G = out_size / 10;

    float* ws = (float*)d_ws;
    float* A      = ws;                                  // z (u16 hi/lo) / h f32
    float* B      = A + (size_t)N * HH;                  // t2b (u16) / t2 f32
    float* C      = B + (size_t)N * HH;                  // act0+hb (u16) / t1 f32
    float* assign = C + (size_t)N * HH;                  // N*8
    float* t4     = assign + (size_t)N * 8;              // G*128
    float* statsA = t4 + (size_t)G * HH;                 // 7*256
    u16* Whi = (u16*)(statsA + 7 * 256);                 // WTOT
    u16* Wlo = Whi + WTOT;                               // WTOT
    int* rowptr = (int*)(Wlo + WTOT);                    // N+1
    int* cursor = rowptr + (N + 1);                      // N (also deg)
    int* colidx = cursor + N;                            // E
    int* bsum   = colidx + E;                            // 256
    int* boff   = bsum + 256;                            // 256
    // aliases:
    u16* zhi  = (u16*)A;
    u16* zlo  = zhi + (size_t)N * HH;
    float* h  = A;
    u16* t2b  = (u16*)B;
    float* t2f = B;
    u16* hb   = (u16*)C;   // act0 / per-layer bf16 h
    float* t1 = C;

    const dim3 B256(256), B128(128), B512(512), B1024(1024);
    const int ntiles = (N + 127) / 128;
    const int gg = ntiles < 512 ? ntiles : 512;
    const int nch = (N + 255) / 256;
    const int e4 = (E + 4 * 256 - 1) / (4 * 256);
    const float invN = 1.f / (float)N;
    const float invG = 1.f / (float)G;

    // weight prep + CSR build + stats clear
    k_prep<<<7, B256, 0, stream>>>(inp_w, mlp1_w, mlp2_w, Whi, Wlo);
    hipMemsetAsync(cursor, 0, (size_t)N * sizeof(int), stream);
    hipMemsetAsync(statsA, 0, 7 * 256 * sizeof(float), stream);
    k_hist<<<e4, B256, 0, stream>>>(ei, cursor, E);
    k_bsum<<<nch, B256, 0, stream>>>(cursor, bsum, N);
    k_scan1<<<1, B256, 0, stream>>>(bsum, boff, rowptr + N, nch);
    k_scan2<<<nch, B256, 0, stream>>>(cursor, boff, rowptr, cursor, N);
    k_fill<<<e4, B256, 0, stream>>>(ei, cursor, colidx, E);

    // hb = bf16(x @ inp_w + inp_b)
    k_mgemm<64, 0, false, false, true><<<gg, B512, 0, stream>>>(
        x, nullptr, nullptr, Whi, Wlo, inp_b, nullptr, nullptr, nullptr, 0.f,
        nullptr, hb, nullptr, N, ntiles);

    for (int l = 0; l < 3; l++) {
        float* sa = statsA + (size_t)(2 * l) * 256;
        float* sb = sa + 256;
        k_gather<<<(N + 1) / 2, B256, 0, stream>>>(hb, rowptr, colidx,
                                                   elin_w + l * HH, elin_b + l * HH,
                                                   zhi, zlo, N);
        // t1 = z @ W1 + b1 (stats -> sa)
        k_mgemm<128, 2, true, true, false><<<gg, B512, 0, stream>>>(
            nullptr, zhi, zlo, Whi + 8192 + (size_t)l * 16384,
            Wlo + 8192 + (size_t)l * 16384, mlp1_b + l * HH,
            nullptr, nullptr, nullptr, 0.f, t1, nullptr, sa, N, ntiles);
        // t2 = relu(bn(t1)) @ W2 + b2 ; bf16 out for l<2, f32 for l==2
        if (l < 2) {
            k_mgemm<128, 1, true, false, true><<<gg, B512, 0, stream>>>(
                t1, nullptr, nullptr, Whi + 8192 + (size_t)(3 + l) * 16384,
                Wlo + 8192 + (size_t)(3 + l) * 16384, mlp2_b + l * HH,
                sa, mlpbn_g + l * HH, mlpbn_b + l * HH, invN,
                nullptr, t2b, sb, N, ntiles);
            k_bnrelu_bf<<<(N * 32 + 255) / 256, B256, 0, stream>>>(
                t2b, sb, bn_g + l * HH, bn_b + l * HH, invN, hb, N * 32);
        } else {
            k_mgemm<128, 1, true, true, false><<<gg, B512, 0, stream>>>(
                t1, nullptr, nullptr, Whi + 8192 + (size_t)(3 + l) * 16384,
                Wlo + 8192 + (size_t)(3 + l) * 16384, mlp2_b + l * HH,
                sa, mlpbn_g + l * HH, mlpbn_b + l * HH, invN,
                t2f, nullptr, sb, N, ntiles);
            k_bnrelu<<<(N * 32 + 255) / 256, B256, 0, stream>>>(
                t2f, sb, bn_g + l * HH, bn_b + l * HH, invN, h, N * 32);
        }
    }

    k_assign<<<(N + 31) / 32, B256, 0, stream>>>(h, gumbel, bh1_w, bh1_b, bh2_w, bh2_b, assign, N);
    float* sc_ = statsA + 6 * 256;
    k_tail<<<G, B1024, 0, stream>>>(h, assign, batch, bm_w, bm_b, ln_g, ln_b,
                                    clf1_w, clf1_b, t4, sc_, N);
    k_clf2<<<G, B128, 0, stream>>>(t4, sc_, clfbn_g, clfbn_b, invG, clf2_w, clf2_b, out);
}

// Round 16
// 496.862 us; speedup vs baseline: 1.5475x; 1.0101x over previous
//
#include <hip/hip_runtime.h>
#include <hip/hip_bf16.h>

// ---------------------------------------------------------------------------
// SoftBlobGIN round 16: R15 + h-elimination — final-layer BN-relu folded into
// the two consumers (k_assign staging, k_tail pool load); k_bnrelu dropped.
// Bit-identical math to R15 elsewhere.
// ---------------------------------------------------------------------------

#define HH 128
typedef unsigned short u16;
typedef unsigned int u32;
typedef __attribute__((ext_vector_type(8))) short bf16x8;
typedef __attribute__((ext_vector_type(4))) float f32x4;

__device__ __forceinline__ void atomAddF(float* p, float v) { unsafeAtomicAdd(p, v); }

__device__ __forceinline__ u16 f2bf(float f) {          // RNE f32->bf16
    u32 u = __float_as_uint(f);
    u += 0x7fffu + ((u >> 16) & 1u);
    return (u16)(u >> 16);
}
__device__ __forceinline__ float bf2f_lo(u32 u) { return __uint_as_float(u << 16); }
__device__ __forceinline__ float bf2f_hi(u32 u) { return __uint_as_float(u & 0xffff0000u); }
__device__ __forceinline__ void split2(float v, u16& hi, u16& lo) {
    u16 h_ = f2bf(v);
    float hf = __uint_as_float(((u32)h_) << 16);
    hi = h_;
    lo = f2bf(v - hf);
}
__device__ __forceinline__ u32 swz(u32 row, u32 kByte, u32 strideB) {
    return (row * strideB + kByte) ^ ((row & 7u) << 4);
}

#define WTOT (8192 + 6 * 16384)

// ---------------- weight prep ----------------
__global__ void k_prep(const float* __restrict__ inp_w, const float* __restrict__ m1,
                       const float* __restrict__ m2, u16* __restrict__ Whi,
                       u16* __restrict__ Wlo) {
    int b = blockIdx.x;  // 0..6
    int t = threadIdx.x; // 256
    if (b == 0) {
        for (int idx = t; idx < 128 * 64; idx += 256) {
            int c = idx >> 6, k = idx & 63;
            u16 hi, lo;
            split2(inp_w[k * 128 + c], hi, lo);
            Whi[idx] = hi; Wlo[idx] = lo;
        }
    } else {
        const float* W = (b <= 3) ? m1 + (size_t)(b - 1) * 16384
                                  : m2 + (size_t)(b - 4) * 16384;
        u16* dh = Whi + 8192 + (size_t)(b - 1) * 16384;
        u16* dl = Wlo + 8192 + (size_t)(b - 1) * 16384;
        for (int idx = t; idx < 16384; idx += 256) {
            int c = idx >> 7, k = idx & 127;
            u16 hi, lo;
            split2(W[k * 128 + c], hi, lo);
            dh[idx] = hi; dl[idx] = lo;
        }
    }
}

// ---------------- CSR build (4 edges/thread) ----------------
__global__ void k_hist(const int* __restrict__ ei, int* __restrict__ deg, int E) {
    int i4 = blockIdx.x * 256 + threadIdx.x;
    int e0 = i4 * 4;
    if (e0 + 3 < E) {
        int4 d = *(const int4*)(ei + E + e0);
        atomicAdd(&deg[d.x], 1);
        atomicAdd(&deg[d.y], 1);
        atomicAdd(&deg[d.z], 1);
        atomicAdd(&deg[d.w], 1);
    } else {
        for (int e = e0; e < E; e++) atomicAdd(&deg[ei[E + e]], 1);
    }
}

__global__ void k_bsum(const int* __restrict__ deg, int* __restrict__ bsum, int N) {
    int t = threadIdx.x;
    int i = blockIdx.x * 256 + t;
    int v = (i < N) ? deg[i] : 0;
    for (int o = 32; o; o >>= 1) v += __shfl_down(v, o);
    __shared__ int ws_[4];
    if ((t & 63) == 0) ws_[t >> 6] = v;
    __syncthreads();
    if (t == 0) bsum[blockIdx.x] = ws_[0] + ws_[1] + ws_[2] + ws_[3];
}

__global__ void k_scan1(const int* __restrict__ bsum, int* __restrict__ boff,
                        int* __restrict__ rowptrN, int nch) {
    int t = threadIdx.x;  // 256
    int v = (t < nch) ? bsum[t] : 0;
    int l = t & 63, w = t >> 6;
    int sv = v;
    for (int o = 1; o < 64; o <<= 1) { int u = __shfl_up(sv, o); if (l >= o) sv += u; }
    __shared__ int wsum[4];
    if (l == 63) wsum[w] = sv;
    __syncthreads();
    int add = 0;
    for (int j = 0; j < w; j++) add += wsum[j];
    if (t < nch) boff[t] = sv - v + add;
    if (t == nch - 1) *rowptrN = sv + add;
}

__global__ void k_scan2(const int* __restrict__ deg, const int* __restrict__ boff,
                        int* __restrict__ rowptr, int* __restrict__ cursor, int N) {
    int b = blockIdx.x, t = threadIdx.x, i = b * 256 + t;
    int v = (i < N) ? deg[i] : 0;
    int l = t & 63, w = t >> 6;
    int sv = v;
    for (int o = 1; o < 64; o <<= 1) { int u = __shfl_up(sv, o); if (l >= o) sv += u; }
    __shared__ int wsum[4];
    if (l == 63) wsum[w] = sv;
    __syncthreads();
    int add = boff[b];
    for (int j = 0; j < w; j++) add += wsum[j];
    if (i < N) { int e = sv - v + add; rowptr[i] = e; cursor[i] = e; }
}

__global__ void k_fill(const int* __restrict__ ei, int* __restrict__ cursor,
                       int* __restrict__ col, int E) {
    int i4 = blockIdx.x * 256 + threadIdx.x;
    int e0 = i4 * 4;
    if (e0 + 3 < E) {
        int4 s = *(const int4*)(ei + e0);
        int4 d = *(const int4*)(ei + E + e0);
        int p0 = atomicAdd(&cursor[d.x], 1);
        int p1 = atomicAdd(&cursor[d.y], 1);
        int p2 = atomicAdd(&cursor[d.z], 1);
        int p3 = atomicAdd(&cursor[d.w], 1);
        col[p0] = s.x;
        col[p1] = s.y;
        col[p2] = s.z;
        col[p3] = s.w;
    } else {
        for (int e = e0; e < E; e++) {
            int pos = atomicAdd(&cursor[ei[E + e]], 1);
            col[pos] = ei[e];
        }
    }
}

// ---------------- MFMA GEMM: A direct from global; B staged in LDS ----------
// MODE 0: f32 input | MODE 1: f32 input + bn-relu | MODE 2: bf16 hi/lo input
template <int KD, int MODE, bool STATS, bool FOUT, bool BOUT>
__global__ __launch_bounds__(512) void k_mgemm(
    const float* __restrict__ inf, const u16* __restrict__ inhi,
    const u16* __restrict__ inlo, const u16* __restrict__ Whi,
    const u16* __restrict__ Wlo, const float* __restrict__ bias,
    const float* __restrict__ statsIn, const float* __restrict__ gamma,
    const float* __restrict__ beta, float invN,
    float* __restrict__ out, u16* __restrict__ outb,
    float* __restrict__ statsOut, int Nrows, int ntiles) {
    __shared__ u16 s_Bhi[128 * KD];
    __shared__ u16 s_Blo[128 * KD];
    __shared__ float s_red[2][8][128];
    __shared__ float s_sc[128], s_sh[128];
    const int t = threadIdx.x;
    constexpr u32 STR = KD * 2;
    constexpr int KCB = KD / 8;
    constexpr int NB = (128 * KCB) / 512;
    constexpr int NF = KD / 32;

#pragma unroll
    for (int i = 0; i < NB; i++) {
        int idx = i * 512 + t;
        int c = idx / KCB, kc = idx % KCB;
        u32 off = swz(c, kc * 16, STR);
        *(uint4*)((char*)s_Bhi + off) = *(const uint4*)(Whi + (size_t)c * KD + kc * 8);
        *(uint4*)((char*)s_Blo + off) = *(const uint4*)(Wlo + (size_t)c * KD + kc * 8);
    }
    if (MODE == 1 && t < 128) {
        float m = statsIn[t] * invN;
        float var = statsIn[128 + t] * invN - m * m;
        float s = gamma[t] * rsqrtf(var + 1e-5f);
        s_sc[t] = s;
        s_sh[t] = beta[t] - m * s;
    }
    __syncthreads();

    const int l = t & 63, w = t >> 6;
    const int c0 = l & 15;
    const int ksub = (l >> 4) * 8;
    const u32 kOffB = (u32)(l >> 4) * 16u;

    for (int tile = blockIdx.x; tile < ntiles; tile += gridDim.x) {
        const int row = tile * 128 + w * 16 + c0;
        const bool rv = row < Nrows;

        bf16x8 ah[NF], al[NF];
        if (MODE == 2) {
#pragma unroll
            for (int kk = 0; kk < NF; kk++) {
                int k0 = kk * 32 + ksub;
                if (rv) {
                    ah[kk] = *(const bf16x8*)(inhi + (size_t)row * KD + k0);
                    al[kk] = *(const bf16x8*)(inlo + (size_t)row * KD + k0);
                } else {
                    uint4 z = {0, 0, 0, 0};
                    ah[kk] = *(bf16x8*)&z;
                    al[kk] = *(bf16x8*)&z;
                }
            }
        } else {
#pragma unroll
            for (int kk = 0; kk < NF; kk++) {
                int k0 = kk * 32 + ksub;
                float4 v0 = {0.f, 0.f, 0.f, 0.f}, v1 = {0.f, 0.f, 0.f, 0.f};
                if (rv) {
                    v0 = *(const float4*)(inf + (size_t)row * KD + k0);
                    v1 = *(const float4*)(inf + (size_t)row * KD + k0 + 4);
                }
                float vv[8] = {v0.x, v0.y, v0.z, v0.w, v1.x, v1.y, v1.z, v1.w};
                uint4 uh, ul;
                u32* ph = (u32*)&uh;
                u32* pl = (u32*)&ul;
#pragma unroll
                for (int p = 0; p < 4; p++) {
                    float a0 = vv[2 * p], a1 = vv[2 * p + 1];
                    if (MODE == 1) {
                        a0 = fmaxf(a0 * s_sc[k0 + 2 * p] + s_sh[k0 + 2 * p], 0.f);
                        a1 = fmaxf(a1 * s_sc[k0 + 2 * p + 1] + s_sh[k0 + 2 * p + 1], 0.f);
                    }
                    u16 h0, l0, h1, l1;
                    split2(a0, h0, l0);
                    split2(a1, h1, l1);
                    ph[p] = (u32)h0 | ((u32)h1 << 16);
                    pl[p] = (u32)l0 | ((u32)l1 << 16);
                }
                ah[kk] = *(bf16x8*)&uh;
                al[kk] = *(bf16x8*)&ul;
            }
        }

        f32x4 acc[8];
#pragma unroll
        for (int n = 0; n < 8; n++) acc[n] = (f32x4){0.f, 0.f, 0.f, 0.f};
#pragma unroll
        for (int kk = 0; kk < NF; kk++) {
            u32 kb = kk * 64 + kOffB;
#pragma unroll
            for (int n = 0; n < 8; n++) {
                u32 ob = swz(n * 16 + c0, kb, STR);
                bf16x8 bh = *(const bf16x8*)((char*)s_Bhi + ob);
                bf16x8 bl = *(const bf16x8*)((char*)s_Blo + ob);
                acc[n] = __builtin_amdgcn_mfma_f32_16x16x32_bf16(ah[kk], bh, acc[n], 0, 0, 0);
                acc[n] = __builtin_amdgcn_mfma_f32_16x16x32_bf16(al[kk], bh, acc[n], 0, 0, 0);
                acc[n] = __builtin_amdgcn_mfma_f32_16x16x32_bf16(ah[kk], bl, acc[n], 0, 0, 0);
            }
        }

        const int rbase = tile * 128 + w * 16 + ((l >> 4) << 2);
#pragma unroll
        for (int n = 0; n < 8; n++) {
            const int colc = n * 16 + c0;
            const float bv = bias[colc];
            float s = 0.f, q = 0.f;
#pragma unroll
            for (int j = 0; j < 4; j++) {
                int gr = rbase + j;
                if (gr < Nrows) {
                    float v = acc[n][j] + bv;
                    if (FOUT) out[(size_t)gr * HH + colc] = v;
                    if (BOUT) outb[(size_t)gr * HH + colc] = f2bf(v);
                    s += v;
                    q += v * v;
                }
            }
            if (STATS) {
                s += __shfl_xor(s, 16); s += __shfl_xor(s, 32);
                q += __shfl_xor(q, 16); q += __shfl_xor(q, 32);
                if (l < 16) {
                    s_red[0][w][n * 16 + l] = s;
                    s_red[1][w][n * 16 + l] = q;
                }
            }
        }
        if (STATS) {
            __syncthreads();
            if (t < 128) {
                float S = 0.f, Q = 0.f;
#pragma unroll
                for (int ww = 0; ww < 8; ww++) { S += s_red[0][ww][t]; Q += s_red[1][ww][t]; }
                atomAddF(&statsOut[t], S);
                atomAddF(&statsOut[HH + t], Q);
            }
            __syncthreads();
        }
    }
}

// ---------------- gather: 2 waves/node, 8-deep unroll (pure form) -----------
__global__ __launch_bounds__(256) void k_gather(
    const u16* __restrict__ hb,
    const int* __restrict__ rowptr, const int* __restrict__ col,
    const float* __restrict__ ew, const float* __restrict__ eb,
    u16* __restrict__ zhi, u16* __restrict__ zlo, int N) {
    __shared__ float2 s_part[2][64];
    const int wv = threadIdx.x >> 6;
    const int lane = threadIdx.x & 63;
    const int node = blockIdx.x * 2 + (wv >> 1);
    const int hf = wv & 1;
    const int c2 = lane * 2;
    float2 acc = {0.f, 0.f};
    const bool valid = node < N;
    float2 ee = {0.f, 0.f};
    if (valid) {
        ee.x = ew[c2] + eb[c2];
        ee.y = ew[c2 + 1] + eb[c2 + 1];
        const int s = rowptr[node], eend = rowptr[node + 1];
        int e = s + hf;
        for (; e + 14 < eend; e += 16) {
            int s0 = col[e], s1 = col[e + 2], s2 = col[e + 4], s3 = col[e + 6];
            int s4 = col[e + 8], s5 = col[e + 10], s6 = col[e + 12], s7 = col[e + 14];
            u32 u0 = *(const u32*)(hb + (size_t)s0 * HH + c2);
            u32 u1 = *(const u32*)(hb + (size_t)s1 * HH + c2);
            u32 u2 = *(const u32*)(hb + (size_t)s2 * HH + c2);
            u32 u3 = *(const u32*)(hb + (size_t)s3 * HH + c2);
            u32 u4 = *(const u32*)(hb + (size_t)s4 * HH + c2);
            u32 u5 = *(const u32*)(hb + (size_t)s5 * HH + c2);
            u32 u6 = *(const u32*)(hb + (size_t)s6 * HH + c2);
            u32 u7 = *(const u32*)(hb + (size_t)s7 * HH + c2);
            acc.x += fmaxf(bf2f_lo(u0) + ee.x, 0.f) + fmaxf(bf2f_lo(u1) + ee.x, 0.f) +
                     fmaxf(bf2f_lo(u2) + ee.x, 0.f) + fmaxf(bf2f_lo(u3) + ee.x, 0.f) +
                     fmaxf(bf2f_lo(u4) + ee.x, 0.f) + fmaxf(bf2f_lo(u5) + ee.x, 0.f) +
                     fmaxf(bf2f_lo(u6) + ee.x, 0.f) + fmaxf(bf2f_lo(u7) + ee.x, 0.f);
            acc.y += fmaxf(bf2f_hi(u0) + ee.y, 0.f) + fmaxf(bf2f_hi(u1) + ee.y, 0.f) +
                     fmaxf(bf2f_hi(u2) + ee.y, 0.f) + fmaxf(bf2f_hi(u3) + ee.y, 0.f) +
                     fmaxf(bf2f_hi(u4) + ee.y, 0.f) + fmaxf(bf2f_hi(u5) + ee.y, 0.f) +
                     fmaxf(bf2f_hi(u6) + ee.y, 0.f) + fmaxf(bf2f_hi(u7) + ee.y, 0.f);
        }
        for (; e + 6 < eend; e += 8) {
            int s0 = col[e], s1 = col[e + 2], s2 = col[e + 4], s3 = col[e + 6];
            u32 u0 = *(const u32*)(hb + (size_t)s0 * HH + c2);
            u32 u1 = *(const u32*)(hb + (size_t)s1 * HH + c2);
            u32 u2 = *(const u32*)(hb + (size_t)s2 * HH + c2);
            u32 u3 = *(const u32*)(hb + (size_t)s3 * HH + c2);
            acc.x += fmaxf(bf2f_lo(u0) + ee.x, 0.f) + fmaxf(bf2f_lo(u1) + ee.x, 0.f) +
                     fmaxf(bf2f_lo(u2) + ee.x, 0.f) + fmaxf(bf2f_lo(u3) + ee.x, 0.f);
            acc.y += fmaxf(bf2f_hi(u0) + ee.y, 0.f) + fmaxf(bf2f_hi(u1) + ee.y, 0.f) +
                     fmaxf(bf2f_hi(u2) + ee.y, 0.f) + fmaxf(bf2f_hi(u3) + ee.y, 0.f);
        }
        for (; e < eend; e += 2) {
            u32 u0 = *(const u32*)(hb + (size_t)col[e] * HH + c2);
            acc.x += fmaxf(bf2f_lo(u0) + ee.x, 0.f);
            acc.y += fmaxf(bf2f_hi(u0) + ee.y, 0.f);
        }
    }
    if (hf) s_part[wv >> 1][lane] = acc;
    __syncthreads();
    if (!hf && valid) {
        float2 p = s_part[wv >> 1][lane];
        u32 un = *(const u32*)(hb + (size_t)node * HH + c2);
        float zx = bf2f_lo(un) + acc.x + p.x;
        float zy = bf2f_hi(un) + acc.y + p.y;
        u16 h0, h1, l0, l1;
        split2(zx, h0, l0);
        split2(zy, h1, l1);
        *(u32*)(zhi + (size_t)node * HH + c2) = (u32)h0 | ((u32)h1 << 16);
        *(u32*)(zlo + (size_t)node * HH + c2) = (u32)l0 | ((u32)l1 << 16);
    }
}

// ---------------- bnrelu bf16->bf16 (layers 0,1) ----------------
__global__ void k_bnrelu_bf(const u16* __restrict__ tb, const float* __restrict__ stats,
                            const float* __restrict__ g, const float* __restrict__ b,
                            float invN, u16* __restrict__ hb, int total4) {
    int i = blockIdx.x * 256 + threadIdx.x;
    if (i >= total4) return;
    int c4 = (i & 31) << 2;
    float sc[4], sh[4];
#pragma unroll
    for (int j = 0; j < 4; j++) {
        float m = stats[c4 + j] * invN;
        float var = stats[128 + c4 + j] * invN - m * m;
        float s = g[c4 + j] * rsqrtf(var + 1e-5f);
        sc[j] = s;
        sh[j] = b[c4 + j] - m * s;
    }
    uint2 v = *(const uint2*)(tb + (size_t)i * 4);
    float o0 = fmaxf(bf2f_lo(v.x) * sc[0] + sh[0], 0.f);
    float o1 = fmaxf(bf2f_hi(v.x) * sc[1] + sh[1], 0.f);
    float o2 = fmaxf(bf2f_lo(v.y) * sc[2] + sh[2], 0.f);
    float o3 = fmaxf(bf2f_hi(v.y) * sc[3] + sh[3], 0.f);
    uint2 p = {(u32)f2bf(o0) | ((u32)f2bf(o1) << 16),
               (u32)f2bf(o2) | ((u32)f2bf(o3) << 16)};
    *(uint2*)(hb + (size_t)i * 4) = p;
}

// ---------------- assign: fused final BN-relu on load -----------------------
__global__ __launch_bounds__(256) void k_assign(
    const float* __restrict__ t2f, const float* __restrict__ stats,
    const float* __restrict__ bng, const float* __restrict__ bnb, float invN,
    const float* __restrict__ gum,
    const float* __restrict__ w1, const float* __restrict__ b1,
    const float* __restrict__ w2, const float* __restrict__ b2,
    float* __restrict__ assign, int N) {
    __shared__ float s_w1[128 * 64];
    __shared__ float s_w2[64 * 8];
    __shared__ float s_h[32][128];
    __shared__ float s_hid[32][64];
    const int t = threadIdx.x;
    const int n0 = blockIdx.x * 32;
    for (int i = t; i < 128 * 64; i += 256) s_w1[i] = w1[i];
    for (int i = t; i < 512; i += 256) s_w2[i] = w2[i];
    for (int i = t; i < 32 * 32; i += 256) {
        int r = i >> 5, c4 = (i & 31) << 2;
        int gn = n0 + r;
        float4 o = {0.f, 0.f, 0.f, 0.f};
        if (gn < N) {
            float4 v = *(const float4*)(t2f + (size_t)gn * HH + c4);
            float vv[4] = {v.x, v.y, v.z, v.w};
            float oo[4];
#pragma unroll
            for (int j = 0; j < 4; j++) {
                float m = stats[c4 + j] * invN;
                float var = stats[128 + c4 + j] * invN - m * m;
                float s = bng[c4 + j] * rsqrtf(var + 1e-5f);
                float sh = bnb[c4 + j] - m * s;
                oo[j] = fmaxf(vv[j] * s + sh, 0.f);
            }
            o.x = oo[0]; o.y = oo[1]; o.z = oo[2]; o.w = oo[3];
        }
        *(float4*)(&s_h[r][c4]) = o;
    }
    __syncthreads();
    for (int o = t; o < 32 * 64; o += 256) {
        int nn = o >> 6, j = o & 63;
        float acc = b1[j];
        for (int k = 0; k < 128; k++) acc = fmaf(s_h[nn][k], s_w1[k * 64 + j], acc);
        s_hid[nn][j] = fmaxf(acc, 0.f);
    }
    __syncthreads();
    int nn = t >> 3, kk = t & 7;
    int gn = n0 + nn;
    float a = b2[kk];
    for (int j = 0; j < 64; j++) a = fmaf(s_hid[nn][j], s_w2[j * 8 + kk], a);
    if (gn < N) a += gum[(size_t)gn * 8 + kk];
    float m = a;
    m = fmaxf(m, __shfl_xor(m, 1));
    m = fmaxf(m, __shfl_xor(m, 2));
    m = fmaxf(m, __shfl_xor(m, 4));
    float e = expf(a - m);
    float s = e;
    s += __shfl_xor(s, 1); s += __shfl_xor(s, 2); s += __shfl_xor(s, 4);
    if (gn < N) assign[(size_t)gn * 8 + kk] = e / s;
}

// ---------------- fused tail: BN-relu + pool + blob + LN + max + clf1 -------
__device__ __forceinline__ int lowerb(const int* __restrict__ arr, int n, int val) {
    int lo = 0, hi = n;
    while (lo < hi) {
        int mid = (lo + hi) >> 1;
        if (arr[mid] < val) lo = mid + 1;
        else hi = mid;
    }
    return lo;
}

__global__ __launch_bounds__(1024) void k_tail(
    const float* __restrict__ t2f, const float* __restrict__ bstats,
    const float* __restrict__ bng, const float* __restrict__ bnb, float invN,
    const float* __restrict__ assign,
    const int* __restrict__ batch, const float* __restrict__ bm_w,
    const float* __restrict__ bm_b, const float* __restrict__ ln_g,
    const float* __restrict__ ln_b, const float* __restrict__ clf1_w,
    const float* __restrict__ clf1_b, float* __restrict__ t4,
    float* __restrict__ stats, int N) {
    __shared__ float4 s_num[4][8][32];
    __shared__ float4 s_gm[4][32];
    __shared__ float s_den[4][8];
    __shared__ float s_numf[8][128];
    __shared__ float s_denf[8];
    __shared__ float s_blob[8][128];
    __shared__ float s_cat[256];
    __shared__ float s_r[16][2];
    const int g = blockIdx.x;
    const int t = threadIdx.x;
    const int ns = t >> 8;
    const int k = (t >> 5) & 7;
    const int lane = t & 31;
    const int c4 = lane << 2;
    const int start = lowerb(batch, N, g);
    const int end = lowerb(batch, N, g + 1);

    // per-thread BN scale/shift for its 4 fixed channels
    float bsc[4], bsh[4];
#pragma unroll
    for (int j = 0; j < 4; j++) {
        float m = bstats[c4 + j] * invN;
        float var = bstats[128 + c4 + j] * invN - m * m;
        float s = bng[c4 + j] * rsqrtf(var + 1e-5f);
        bsc[j] = s;
        bsh[j] = bnb[c4 + j] - m * s;
    }

    float4 an = {0.f, 0.f, 0.f, 0.f};
    float4 gm = {0.f, 0.f, 0.f, 0.f};
    float ad = 0.f;
    for (int n = start + ns; n < end; n += 4) {
        float a = assign[(size_t)n * 8 + k];
        float4 tv = *(const float4*)(t2f + (size_t)n * HH + c4);
        float4 hv;
        hv.x = fmaxf(tv.x * bsc[0] + bsh[0], 0.f);
        hv.y = fmaxf(tv.y * bsc[1] + bsh[1], 0.f);
        hv.z = fmaxf(tv.z * bsc[2] + bsh[2], 0.f);
        hv.w = fmaxf(tv.w * bsc[3] + bsh[3], 0.f);
        an.x = fmaf(a, hv.x, an.x);
        an.y = fmaf(a, hv.y, an.y);
        an.z = fmaf(a, hv.z, an.z);
        an.w = fmaf(a, hv.w, an.w);
        if (k == 0) { gm.x += hv.x; gm.y += hv.y; gm.z += hv.z; gm.w += hv.w; }
        ad += a;
    }
    s_num[ns][k][lane] = an;
    if (k == 0) s_gm[ns][lane] = gm;
    if (lane == 0) s_den[ns][k] = ad;
    __syncthreads();
    if (t < 256) {
        float4 a0 = s_num[0][k][lane], a1 = s_num[1][k][lane];
        float4 a2 = s_num[2][k][lane], a3 = s_num[3][k][lane];
        s_numf[k][c4 + 0] = a0.x + a1.x + a2.x + a3.x;
        s_numf[k][c4 + 1] = a0.y + a1.y + a2.y + a3.y;
        s_numf[k][c4 + 2] = a0.z + a1.z + a2.z + a3.z;
        s_numf[k][c4 + 3] = a0.w + a1.w + a2.w + a3.w;
        if (t < 32) {
            float4 g0 = s_gm[0][lane], g1 = s_gm[1][lane];
            float4 g2 = s_gm[2][lane], g3 = s_gm[3][lane];
            int cnt = end - start;
            float inv = 1.f / (float)(cnt > 0 ? cnt : 1);
            s_cat[c4 + 0] = (g0.x + g1.x + g2.x + g3.x) * inv;
            s_cat[c4 + 1] = (g0.y + g1.y + g2.y + g3.y) * inv;
            s_cat[c4 + 2] = (g0.z + g1.z + g2.z + g3.z) * inv;
            s_cat[c4 + 3] = (g0.w + g1.w + g2.w + g3.w) * inv;
        }
        if (t < 8) s_denf[t] = s_den[0][t] + s_den[1][t] + s_den[2][t] + s_den[3][t];
    }
    __syncthreads();

    {
        const int kk = t >> 7;
        const int c = t & 127;
        const float d = 1.f / (s_denf[kk] + 1e-8f);
        float acc = bm_b[c];
        for (int j = 0; j < 128; j++)
            acc = fmaf(s_numf[kk][j] * d, bm_w[j * HH + c], acc);
        float y = fmaxf(acc, 0.f);
        float s = y, q = y * y;
        for (int off = 32; off > 0; off >>= 1) {
            s += __shfl_down(s, off);
            q += __shfl_down(q, off);
        }
        const int wv = t >> 6;
        if ((t & 63) == 0) { s_r[wv][0] = s; s_r[wv][1] = q; }
        __syncthreads();
        float S = s_r[kk * 2][0] + s_r[kk * 2 + 1][0];
        float Q = s_r[kk * 2][1] + s_r[kk * 2 + 1][1];
        float m = S * (1.f / 128.f);
        float var = Q * (1.f / 128.f) - m * m;
        s_blob[kk][c] = (y - m) * rsqrtf(var + 1e-5f) * ln_g[c] + ln_b[c];
    }
    __syncthreads();

    if (t < 128) {
        float m = s_blob[0][t];
#pragma unroll
        for (int kk = 1; kk < 8; kk++) m = fmaxf(m, s_blob[kk][t]);
        s_cat[128 + t] = m;
    }
    __syncthreads();

    if (t < 128) {
        float acc = clf1_b[t];
        for (int j = 0; j < 256; j++) acc = fmaf(s_cat[j], clf1_w[j * HH + t], acc);
        t4[(size_t)g * HH + t] = acc;
        atomAddF(&stats[t], acc);
        atomAddF(&stats[HH + t], acc * acc);
    }
}

__global__ void k_clf2(const float* __restrict__ t4, const float* __restrict__ stats,
                       const float* __restrict__ g_, const float* __restrict__ b_,
                       float invG, const float* __restrict__ w,
                       const float* __restrict__ bias, float* __restrict__ out) {
    int g = blockIdx.x;
    int t = threadIdx.x;  // 128
    __shared__ float s[128];
    float m = stats[t] * invG;
    float var = stats[128 + t] * invG - m * m;
    float sc = g_[t] * rsqrtf(var + 1e-5f);
    float sh = b_[t] - m * sc;
    s[t] = fmaxf(t4[(size_t)g * HH + t] * sc + sh, 0.f);
    __syncthreads();
    if (t < 10) {
        float acc = bias[t];
        for (int j = 0; j < 128; j++) acc = fmaf(s[j], w[j * 10 + t], acc);
        out[(size_t)g * 10 + t] = acc;
    }
}

extern "C" void kernel_launch(void* const* d_in, const int* in_sizes, int n_in,
                              void* d_out, int out_size, void* d_ws, size_t ws_size,
                              hipStream_t stream) {
    const float* x      = (const float*)d_in[0];
    const int*   ei     = (const int*)d_in[1];
    const int*   batch  = (const int*)d_in[2];
    const float* gumbel = (const float*)d_in[3];
    const float* inp_w  = (const float*)d_in[4];
    const float* inp_b  = (const float*)d_in[5];
    const float* elin_w = (const float*)d_in[6];
    const float* elin_b = (const float*)d_in[7];
    const float* mlp1_w = (const float*)d_in[8];
    const float* mlp1_b = (const float*)d_in[9];
    const float* mlpbn_g = (const float*)d_in[10];
    const float* mlpbn_b = (const float*)d_in[11];
    const float* mlp2_w = (const float*)d_in[12];
    const float* mlp2_b = (const float*)d_in[13];
    const float* bn_g   = (const float*)d_in[14];
    const float* bn_b   = (const float*)d_in[15];
    const float* bh1_w  = (const float*)d_in[16];
    const float* bh1_b  = (const float*)d_in[17];
    const float* bh2_w  = (const float*)d_in[18];
    const float* bh2_b  = (const float*)d_in[19];
    const float* bm_w   = (const float*)d_in[20];
    const float* bm_b   = (const float*)d_in[21];
    const float* ln_g   = (const float*)d_in[22];
    const float* ln_b   = (const float*)d_in[23];
    const float* clf1_w = (const float*)d_in[24];
    const float* clf1_b = (const float*)d_in[25];
    const float* clfbn_g = (const float*)d_in[26];
    const float* clfbn_b = (const float*)d_in[27];
    const float* clf2_w = (const float*)d_in[28];
    const float* clf2_b = (const float*)d_in[29];
    float* out = (float*)d_out;

    const int N = in_sizes[0] / 64;
    const int E = in_sizes[1] / 2;
    const int G = out_size / 10;

    float* ws = (float*)d_ws;
    float* A      = ws;                                  // z (u16 hi/lo)
    float* B      = A + (size_t)N * HH;                  // t2b (u16) / t2 f32
    float* C      = B + (size_t)N * HH;                  // act0+hb (u16) / t1 f32
    float* assign = C + (size_t)N * HH;                  // N*8
    float* t4     = assign + (size_t)N * 8;              // G*128
    float* statsA = t4 + (size_t)G * HH;                 // 7*256
    u16* Whi = (u16*)(statsA + 7 * 256);                 // WTOT
    u16* Wlo = Whi + WTOT;                               // WTOT
    int* rowptr = (int*)(Wlo + WTOT);                    // N+1
    int* cursor = rowptr + (N + 1);                      // N (also deg)
    int* colidx = cursor + N;                            // E
    int* bsum   = colidx + E;                            // 256
    int* boff   = bsum + 256;                            // 256
    // aliases:
    u16* zhi  = (u16*)A;
    u16* zlo  = zhi + (size_t)N * HH;
    u16* t2b  = (u16*)B;
    float* t2f = B;
    u16* hb   = (u16*)C;   // act0 / per-layer bf16 h
    float* t1 = C;

    const dim3 B256(256), B128(128), B512(512), B1024(1024);
    const int ntiles = (N + 127) / 128;
    const int gg = ntiles < 512 ? ntiles : 512;
    const int nch = (N + 255) / 256;
    const int e4 = (E + 4 * 256 - 1) / (4 * 256);
    const float invN = 1.f / (float)N;
    const float invG = 1.f / (float)G;

    // weight prep + CSR build + stats clear
    k_prep<<<7, B256, 0, stream>>>(inp_w, mlp1_w, mlp2_w, Whi, Wlo);
    hipMemsetAsync(cursor, 0, (size_t)N * sizeof(int), stream);
    hipMemsetAsync(statsA, 0, 7 * 256 * sizeof(float), stream);
    k_hist<<<e4, B256, 0, stream>>>(ei, cursor, E);
    k_bsum<<<nch, B256, 0, stream>>>(cursor, bsum, N);
    k_scan1<<<1, B256, 0, stream>>>(bsum, boff, rowptr + N, nch);
    k_scan2<<<nch, B256, 0, stream>>>(cursor, boff, rowptr, cursor, N);
    k_fill<<<e4, B256, 0, stream>>>(ei, cursor, colidx, E);

    // hb = bf16(x @ inp_w + inp_b)
    k_mgemm<64, 0, false, false, true><<<gg, B512, 0, stream>>>(
        x, nullptr, nullptr, Whi, Wlo, inp_b, nullptr, nullptr, nullptr, 0.f,
        nullptr, hb, nullptr, N, ntiles);

    for (int l = 0; l < 3; l++) {
        float* sa = statsA + (size_t)(2 * l) * 256;
        float* sb = sa + 256;
        k_gather<<<(N + 1) / 2, B256, 0, stream>>>(hb, rowptr, colidx,
                                                   elin_w + l * HH, elin_b + l * HH,
                                                   zhi, zlo, N);
        // t1 = z @ W1 + b1 (stats -> sa)
        k_mgemm<128, 2, true, true, false><<<gg, B512, 0, stream>>>(
            nullptr, zhi, zlo, Whi + 8192 + (size_t)l * 16384,
            Wlo + 8192 + (size_t)l * 16384, mlp1_b + l * HH,
            nullptr, nullptr, nullptr, 0.f, t1, nullptr, sa, N, ntiles);
        // t2 = relu(bn(t1)) @ W2 + b2 ; bf16 out for l<2, f32 for l==2
        if (l < 2) {
            k_mgemm<128, 1, true, false, true><<<gg, B512, 0, stream>>>(
                t1, nullptr, nullptr, Whi + 8192 + (size_t)(3 + l) * 16384,
                Wlo + 8192 + (size_t)(3 + l) * 16384, mlp2_b + l * HH,
                sa, mlpbn_g + l * HH, mlpbn_b + l * HH, invN,
                nullptr, t2b, sb, N, ntiles);
            k_bnrelu_bf<<<(N * 32 + 255) / 256, B256, 0, stream>>>(
                t2b, sb, bn_g + l * HH, bn_b + l * HH, invN, hb, N * 32);
        } else {
            k_mgemm<128, 1, true, true, false><<<gg, B512, 0, stream>>>(
                t1, nullptr, nullptr, Whi + 8192 + (size_t)(3 + l) * 16384,
                Wlo + 8192 + (size_t)(3 + l) * 16384, mlp2_b + l * HH,
                sa, mlpbn_g + l * HH, mlpbn_b + l * HH, invN,
                t2f, nullptr, sb, N, ntiles);
        }
    }

    float* sb2 = statsA + 5 * 256;   // stats of final t2
    k_assign<<<(N + 31) / 32, B256, 0, stream>>>(
        t2f, sb2, bn_g + 2 * HH, bn_b + 2 * HH, invN,
        gumbel, bh1_w, bh1_b, bh2_w, bh2_b, assign, N);
    float* sc_ = statsA + 6 * 256;
    k_tail<<<G, B1024, 0, stream>>>(t2f, sb2, bn_g + 2 * HH, bn_b + 2 * HH, invN,
                                    assign, batch, bm_w, bm_b, ln_g, ln_b,
                                    clf1_w, clf1_b, t4, sc_, N);
    k_clf2<<<G, B128, 0, stream>>>(t4, sc_, clfbn_g, clfbn_b, invG, clf2_w, clf2_b, out);
}

// Round 17
// 466.842 us; speedup vs baseline: 1.6470x; 1.0643x over previous
//
#include <hip/hip_runtime.h>
#include <hip/hip_bf16.h>

// ---------------------------------------------------------------------------
// SoftBlobGIN round 17: R16 + atomic-free k_fill (hist records per-edge
// arrival rank; fill computes pos = rowptr[dst] + rank with a plain L2 read).
// Everything else identical to R16.
// ---------------------------------------------------------------------------

#define HH 128
typedef unsigned short u16;
typedef unsigned int u32;
typedef __attribute__((ext_vector_type(8))) short bf16x8;
typedef __attribute__((ext_vector_type(4))) float f32x4;

__device__ __forceinline__ void atomAddF(float* p, float v) { unsafeAtomicAdd(p, v); }

__device__ __forceinline__ u16 f2bf(float f) {          // RNE f32->bf16
    u32 u = __float_as_uint(f);
    u += 0x7fffu + ((u >> 16) & 1u);
    return (u16)(u >> 16);
}
__device__ __forceinline__ float bf2f_lo(u32 u) { return __uint_as_float(u << 16); }
__device__ __forceinline__ float bf2f_hi(u32 u) { return __uint_as_float(u & 0xffff0000u); }
__device__ __forceinline__ void split2(float v, u16& hi, u16& lo) {
    u16 h_ = f2bf(v);
    float hf = __uint_as_float(((u32)h_) << 16);
    hi = h_;
    lo = f2bf(v - hf);
}
__device__ __forceinline__ u32 swz(u32 row, u32 kByte, u32 strideB) {
    return (row * strideB + kByte) ^ ((row & 7u) << 4);
}

#define WTOT (8192 + 6 * 16384)

// ---------------- weight prep ----------------
__global__ void k_prep(const float* __restrict__ inp_w, const float* __restrict__ m1,
                       const float* __restrict__ m2, u16* __restrict__ Whi,
                       u16* __restrict__ Wlo) {
    int b = blockIdx.x;  // 0..6
    int t = threadIdx.x; // 256
    if (b == 0) {
        for (int idx = t; idx < 128 * 64; idx += 256) {
            int c = idx >> 6, k = idx & 63;
            u16 hi, lo;
            split2(inp_w[k * 128 + c], hi, lo);
            Whi[idx] = hi; Wlo[idx] = lo;
        }
    } else {
        const float* W = (b <= 3) ? m1 + (size_t)(b - 1) * 16384
                                  : m2 + (size_t)(b - 4) * 16384;
        u16* dh = Whi + 8192 + (size_t)(b - 1) * 16384;
        u16* dl = Wlo + 8192 + (size_t)(b - 1) * 16384;
        for (int idx = t; idx < 16384; idx += 256) {
            int c = idx >> 7, k = idx & 127;
            u16 hi, lo;
            split2(W[k * 128 + c], hi, lo);
            dh[idx] = hi; dl[idx] = lo;
        }
    }
}

// ---------------- CSR build ----------------
// hist: deg count + per-edge arrival rank (eorder)
__global__ void k_hist(const int* __restrict__ ei, int* __restrict__ deg,
                       int* __restrict__ eorder, int E) {
    int i4 = blockIdx.x * 256 + threadIdx.x;
    int e0 = i4 * 4;
    if (e0 + 3 < E) {
        int4 d = *(const int4*)(ei + E + e0);
        int4 o;
        o.x = atomicAdd(&deg[d.x], 1);
        o.y = atomicAdd(&deg[d.y], 1);
        o.z = atomicAdd(&deg[d.z], 1);
        o.w = atomicAdd(&deg[d.w], 1);
        *(int4*)(eorder + e0) = o;
    } else {
        for (int e = e0; e < E; e++) eorder[e] = atomicAdd(&deg[ei[E + e]], 1);
    }
}

__global__ void k_bsum(const int* __restrict__ deg, int* __restrict__ bsum, int N) {
    int t = threadIdx.x;
    int i = blockIdx.x * 256 + t;
    int v = (i < N) ? deg[i] : 0;
    for (int o = 32; o; o >>= 1) v += __shfl_down(v, o);
    __shared__ int ws_[4];
    if ((t & 63) == 0) ws_[t >> 6] = v;
    __syncthreads();
    if (t == 0) bsum[blockIdx.x] = ws_[0] + ws_[1] + ws_[2] + ws_[3];
}

__global__ void k_scan1(const int* __restrict__ bsum, int* __restrict__ boff,
                        int* __restrict__ rowptrN, int nch) {
    int t = threadIdx.x;  // 256
    int v = (t < nch) ? bsum[t] : 0;
    int l = t & 63, w = t >> 6;
    int sv = v;
    for (int o = 1; o < 64; o <<= 1) { int u = __shfl_up(sv, o); if (l >= o) sv += u; }
    __shared__ int wsum[4];
    if (l == 63) wsum[w] = sv;
    __syncthreads();
    int add = 0;
    for (int j = 0; j < w; j++) add += wsum[j];
    if (t < nch) boff[t] = sv - v + add;
    if (t == nch - 1) *rowptrN = sv + add;
}

__global__ void k_scan2(const int* __restrict__ deg, const int* __restrict__ boff,
                        int* __restrict__ rowptr, int N) {
    int b = blockIdx.x, t = threadIdx.x, i = b * 256 + t;
    int v = (i < N) ? deg[i] : 0;
    int l = t & 63, w = t >> 6;
    int sv = v;
    for (int o = 1; o < 64; o <<= 1) { int u = __shfl_up(sv, o); if (l >= o) sv += u; }
    __shared__ int wsum[4];
    if (l == 63) wsum[w] = sv;
    __syncthreads();
    int add = boff[b];
    for (int j = 0; j < w; j++) add += wsum[j];
    if (i < N) rowptr[i] = sv - v + add;
}

// fill: atomic-free — pos = rowptr[dst] + eorder[e]
__global__ void k_fill(const int* __restrict__ ei, const int* __restrict__ rowptr,
                       const int* __restrict__ eorder, int* __restrict__ col, int E) {
    int i4 = blockIdx.x * 256 + threadIdx.x;
    int e0 = i4 * 4;
    if (e0 + 3 < E) {
        int4 s = *(const int4*)(ei + e0);
        int4 d = *(const int4*)(ei + E + e0);
        int4 o = *(const int4*)(eorder + e0);
        col[rowptr[d.x] + o.x] = s.x;
        col[rowptr[d.y] + o.y] = s.y;
        col[rowptr[d.z] + o.z] = s.z;
        col[rowptr[d.w] + o.w] = s.w;
    } else {
        for (int e = e0; e < E; e++)
            col[rowptr[ei[E + e]] + eorder[e]] = ei[e];
    }
}

// ---------------- MFMA GEMM: A direct from global; B staged in LDS ----------
// MODE 0: f32 input | MODE 1: f32 input + bn-relu | MODE 2: bf16 hi/lo input
template <int KD, int MODE, bool STATS, bool FOUT, bool BOUT>
__global__ __launch_bounds__(512) void k_mgemm(
    const float* __restrict__ inf, const u16* __restrict__ inhi,
    const u16* __restrict__ inlo, const u16* __restrict__ Whi,
    const u16* __restrict__ Wlo, const float* __restrict__ bias,
    const float* __restrict__ statsIn, const float* __restrict__ gamma,
    const float* __restrict__ beta, float invN,
    float* __restrict__ out, u16* __restrict__ outb,
    float* __restrict__ statsOut, int Nrows, int ntiles) {
    __shared__ u16 s_Bhi[128 * KD];
    __shared__ u16 s_Blo[128 * KD];
    __shared__ float s_red[2][8][128];
    __shared__ float s_sc[128], s_sh[128];
    const int t = threadIdx.x;
    constexpr u32 STR = KD * 2;
    constexpr int KCB = KD / 8;
    constexpr int NB = (128 * KCB) / 512;
    constexpr int NF = KD / 32;

#pragma unroll
    for (int i = 0; i < NB; i++) {
        int idx = i * 512 + t;
        int c = idx / KCB, kc = idx % KCB;
        u32 off = swz(c, kc * 16, STR);
        *(uint4*)((char*)s_Bhi + off) = *(const uint4*)(Whi + (size_t)c * KD + kc * 8);
        *(uint4*)((char*)s_Blo + off) = *(const uint4*)(Wlo + (size_t)c * KD + kc * 8);
    }
    if (MODE == 1 && t < 128) {
        float m = statsIn[t] * invN;
        float var = statsIn[128 + t] * invN - m * m;
        float s = gamma[t] * rsqrtf(var + 1e-5f);
        s_sc[t] = s;
        s_sh[t] = beta[t] - m * s;
    }
    __syncthreads();

    const int l = t & 63, w = t >> 6;
    const int c0 = l & 15;
    const int ksub = (l >> 4) * 8;
    const u32 kOffB = (u32)(l >> 4) * 16u;

    for (int tile = blockIdx.x; tile < ntiles; tile += gridDim.x) {
        const int row = tile * 128 + w * 16 + c0;
        const bool rv = row < Nrows;

        bf16x8 ah[NF], al[NF];
        if (MODE == 2) {
#pragma unroll
            for (int kk = 0; kk < NF; kk++) {
                int k0 = kk * 32 + ksub;
                if (rv) {
                    ah[kk] = *(const bf16x8*)(inhi + (size_t)row * KD + k0);
                    al[kk] = *(const bf16x8*)(inlo + (size_t)row * KD + k0);
                } else {
                    uint4 z = {0, 0, 0, 0};
                    ah[kk] = *(bf16x8*)&z;
                    al[kk] = *(bf16x8*)&z;
                }
            }
        } else {
#pragma unroll
            for (int kk = 0; kk < NF; kk++) {
                int k0 = kk * 32 + ksub;
                float4 v0 = {0.f, 0.f, 0.f, 0.f}, v1 = {0.f, 0.f, 0.f, 0.f};
                if (rv) {
                    v0 = *(const float4*)(inf + (size_t)row * KD + k0);
                    v1 = *(const float4*)(inf + (size_t)row * KD + k0 + 4);
                }
                float vv[8] = {v0.x, v0.y, v0.z, v0.w, v1.x, v1.y, v1.z, v1.w};
                uint4 uh, ul;
                u32* ph = (u32*)&uh;
                u32* pl = (u32*)&ul;
#pragma unroll
                for (int p = 0; p < 4; p++) {
                    float a0 = vv[2 * p], a1 = vv[2 * p + 1];
                    if (MODE == 1) {
                        a0 = fmaxf(a0 * s_sc[k0 + 2 * p] + s_sh[k0 + 2 * p], 0.f);
                        a1 = fmaxf(a1 * s_sc[k0 + 2 * p + 1] + s_sh[k0 + 2 * p + 1], 0.f);
                    }
                    u16 h0, l0, h1, l1;
                    split2(a0, h0, l0);
                    split2(a1, h1, l1);
                    ph[p] = (u32)h0 | ((u32)h1 << 16);
                    pl[p] = (u32)l0 | ((u32)l1 << 16);
                }
                ah[kk] = *(bf16x8*)&uh;
                al[kk] = *(bf16x8*)&ul;
            }
        }

        f32x4 acc[8];
#pragma unroll
        for (int n = 0; n < 8; n++) acc[n] = (f32x4){0.f, 0.f, 0.f, 0.f};
#pragma unroll
        for (int kk = 0; kk < NF; kk++) {
            u32 kb = kk * 64 + kOffB;
#pragma unroll
            for (int n = 0; n < 8; n++) {
                u32 ob = swz(n * 16 + c0, kb, STR);
                bf16x8 bh = *(const bf16x8*)((char*)s_Bhi + ob);
                bf16x8 bl = *(const bf16x8*)((char*)s_Blo + ob);
                acc[n] = __builtin_amdgcn_mfma_f32_16x16x32_bf16(ah[kk], bh, acc[n], 0, 0, 0);
                acc[n] = __builtin_amdgcn_mfma_f32_16x16x32_bf16(al[kk], bh, acc[n], 0, 0, 0);
                acc[n] = __builtin_amdgcn_mfma_f32_16x16x32_bf16(ah[kk], bl, acc[n], 0, 0, 0);
            }
        }

        const int rbase = tile * 128 + w * 16 + ((l >> 4) << 2);
#pragma unroll
        for (int n = 0; n < 8; n++) {
            const int colc = n * 16 + c0;
            const float bv = bias[colc];
            float s = 0.f, q = 0.f;
#pragma unroll
            for (int j = 0; j < 4; j++) {
                int gr = rbase + j;
                if (gr < Nrows) {
                    float v = acc[n][j] + bv;
                    if (FOUT) out[(size_t)gr * HH + colc] = v;
                    if (BOUT) outb[(size_t)gr * HH + colc] = f2bf(v);
                    s += v;
                    q += v * v;
                }
            }
            if (STATS) {
                s += __shfl_xor(s, 16); s += __shfl_xor(s, 32);
                q += __shfl_xor(q, 16); q += __shfl_xor(q, 32);
                if (l < 16) {
                    s_red[0][w][n * 16 + l] = s;
                    s_red[1][w][n * 16 + l] = q;
                }
            }
        }
        if (STATS) {
            __syncthreads();
            if (t < 128) {
                float S = 0.f, Q = 0.f;
#pragma unroll
                for (int ww = 0; ww < 8; ww++) { S += s_red[0][ww][t]; Q += s_red[1][ww][t]; }
                atomAddF(&statsOut[t], S);
                atomAddF(&statsOut[HH + t], Q);
            }
            __syncthreads();
        }
    }
}

// ---------------- gather: 2 waves/node, 8-deep unroll (pure form) -----------
__global__ __launch_bounds__(256) void k_gather(
    const u16* __restrict__ hb,
    const int* __restrict__ rowptr, const int* __restrict__ col,
    const float* __restrict__ ew, const float* __restrict__ eb,
    u16* __restrict__ zhi, u16* __restrict__ zlo, int N) {
    __shared__ float2 s_part[2][64];
    const int wv = threadIdx.x >> 6;
    const int lane = threadIdx.x & 63;
    const int node = blockIdx.x * 2 + (wv >> 1);
    const int hf = wv & 1;
    const int c2 = lane * 2;
    float2 acc = {0.f, 0.f};
    const bool valid = node < N;
    float2 ee = {0.f, 0.f};
    if (valid) {
        ee.x = ew[c2] + eb[c2];
        ee.y = ew[c2 + 1] + eb[c2 + 1];
        const int s = rowptr[node], eend = rowptr[node + 1];
        int e = s + hf;
        for (; e + 14 < eend; e += 16) {
            int s0 = col[e], s1 = col[e + 2], s2 = col[e + 4], s3 = col[e + 6];
            int s4 = col[e + 8], s5 = col[e + 10], s6 = col[e + 12], s7 = col[e + 14];
            u32 u0 = *(const u32*)(hb + (size_t)s0 * HH + c2);
            u32 u1 = *(const u32*)(hb + (size_t)s1 * HH + c2);
            u32 u2 = *(const u32*)(hb + (size_t)s2 * HH + c2);
            u32 u3 = *(const u32*)(hb + (size_t)s3 * HH + c2);
            u32 u4 = *(const u32*)(hb + (size_t)s4 * HH + c2);
            u32 u5 = *(const u32*)(hb + (size_t)s5 * HH + c2);
            u32 u6 = *(const u32*)(hb + (size_t)s6 * HH + c2);
            u32 u7 = *(const u32*)(hb + (size_t)s7 * HH + c2);
            acc.x += fmaxf(bf2f_lo(u0) + ee.x, 0.f) + fmaxf(bf2f_lo(u1) + ee.x, 0.f) +
                     fmaxf(bf2f_lo(u2) + ee.x, 0.f) + fmaxf(bf2f_lo(u3) + ee.x, 0.f) +
                     fmaxf(bf2f_lo(u4) + ee.x, 0.f) + fmaxf(bf2f_lo(u5) + ee.x, 0.f) +
                     fmaxf(bf2f_lo(u6) + ee.x, 0.f) + fmaxf(bf2f_lo(u7) + ee.x, 0.f);
            acc.y += fmaxf(bf2f_hi(u0) + ee.y, 0.f) + fmaxf(bf2f_hi(u1) + ee.y, 0.f) +
                     fmaxf(bf2f_hi(u2) + ee.y, 0.f) + fmaxf(bf2f_hi(u3) + ee.y, 0.f) +
                     fmaxf(bf2f_hi(u4) + ee.y, 0.f) + fmaxf(bf2f_hi(u5) + ee.y, 0.f) +
                     fmaxf(bf2f_hi(u6) + ee.y, 0.f) + fmaxf(bf2f_hi(u7) + ee.y, 0.f);
        }
        for (; e + 6 < eend; e += 8) {
            int s0 = col[e], s1 = col[e + 2], s2 = col[e + 4], s3 = col[e + 6];
            u32 u0 = *(const u32*)(hb + (size_t)s0 * HH + c2);
            u32 u1 = *(const u32*)(hb + (size_t)s1 * HH + c2);
            u32 u2 = *(const u32*)(hb + (size_t)s2 * HH + c2);
            u32 u3 = *(const u32*)(hb + (size_t)s3 * HH + c2);
            acc.x += fmaxf(bf2f_lo(u0) + ee.x, 0.f) + fmaxf(bf2f_lo(u1) + ee.x, 0.f) +
                     fmaxf(bf2f_lo(u2) + ee.x, 0.f) + fmaxf(bf2f_lo(u3) + ee.x, 0.f);
            acc.y += fmaxf(bf2f_hi(u0) + ee.y, 0.f) + fmaxf(bf2f_hi(u1) + ee.y, 0.f) +
                     fmaxf(bf2f_hi(u2) + ee.y, 0.f) + fmaxf(bf2f_hi(u3) + ee.y, 0.f);
        }
        for (; e < eend; e += 2) {
            u32 u0 = *(const u32*)(hb + (size_t)col[e] * HH + c2);
            acc.x += fmaxf(bf2f_lo(u0) + ee.x, 0.f);
            acc.y += fmaxf(bf2f_hi(u0) + ee.y, 0.f);
        }
    }
    if (hf) s_part[wv >> 1][lane] = acc;
    __syncthreads();
    if (!hf && valid) {
        float2 p = s_part[wv >> 1][lane];
        u32 un = *(const u32*)(hb + (size_t)node * HH + c2);
        float zx = bf2f_lo(un) + acc.x + p.x;
        float zy = bf2f_hi(un) + acc.y + p.y;
        u16 h0, h1, l0, l1;
        split2(zx, h0, l0);
        split2(zy, h1, l1);
        *(u32*)(zhi + (size_t)node * HH + c2) = (u32)h0 | ((u32)h1 << 16);
        *(u32*)(zlo + (size_t)node * HH + c2) = (u32)l0 | ((u32)l1 << 16);
    }
}

// ---------------- bnrelu bf16->bf16 (layers 0,1) ----------------
__global__ void k_bnrelu_bf(const u16* __restrict__ tb, const float* __restrict__ stats,
                            const float* __restrict__ g, const float* __restrict__ b,
                            float invN, u16* __restrict__ hb, int total4) {
    int i = blockIdx.x * 256 + threadIdx.x;
    if (i >= total4) return;
    int c4 = (i & 31) << 2;
    float sc[4], sh[4];
#pragma unroll
    for (int j = 0; j < 4; j++) {
        float m = stats[c4 + j] * invN;
        float var = stats[128 + c4 + j] * invN - m * m;
        float s = g[c4 + j] * rsqrtf(var + 1e-5f);
        sc[j] = s;
        sh[j] = b[c4 + j] - m * s;
    }
    uint2 v = *(const uint2*)(tb + (size_t)i * 4);
    float o0 = fmaxf(bf2f_lo(v.x) * sc[0] + sh[0], 0.f);
    float o1 = fmaxf(bf2f_hi(v.x) * sc[1] + sh[1], 0.f);
    float o2 = fmaxf(bf2f_lo(v.y) * sc[2] + sh[2], 0.f);
    float o3 = fmaxf(bf2f_hi(v.y) * sc[3] + sh[3], 0.f);
    uint2 p = {(u32)f2bf(o0) | ((u32)f2bf(o1) << 16),
               (u32)f2bf(o2) | ((u32)f2bf(o3) << 16)};
    *(uint2*)(hb + (size_t)i * 4) = p;
}

// ---------------- assign: fused final BN-relu on load -----------------------
__global__ __launch_bounds__(256) void k_assign(
    const float* __restrict__ t2f, const float* __restrict__ stats,
    const float* __restrict__ bng, const float* __restrict__ bnb, float invN,
    const float* __restrict__ gum,
    const float* __restrict__ w1, const float* __restrict__ b1,
    const float* __restrict__ w2, const float* __restrict__ b2,
    float* __restrict__ assign, int N) {
    __shared__ float s_w1[128 * 64];
    __shared__ float s_w2[64 * 8];
    __shared__ float s_h[32][128];
    __shared__ float s_hid[32][64];
    const int t = threadIdx.x;
    const int n0 = blockIdx.x * 32;
    for (int i = t; i < 128 * 64; i += 256) s_w1[i] = w1[i];
    for (int i = t; i < 512; i += 256) s_w2[i] = w2[i];
    for (int i = t; i < 32 * 32; i += 256) {
        int r = i >> 5, c4 = (i & 31) << 2;
        int gn = n0 + r;
        float4 o = {0.f, 0.f, 0.f, 0.f};
        if (gn < N) {
            float4 v = *(const float4*)(t2f + (size_t)gn * HH + c4);
            float vv[4] = {v.x, v.y, v.z, v.w};
            float oo[4];
#pragma unroll
            for (int j = 0; j < 4; j++) {
                float m = stats[c4 + j] * invN;
                float var = stats[128 + c4 + j] * invN - m * m;
                float s = bng[c4 + j] * rsqrtf(var + 1e-5f);
                float sh = bnb[c4 + j] - m * s;
                oo[j] = fmaxf(vv[j] * s + sh, 0.f);
            }
            o.x = oo[0]; o.y = oo[1]; o.z = oo[2]; o.w = oo[3];
        }
        *(float4*)(&s_h[r][c4]) = o;
    }
    __syncthreads();
    for (int o = t; o < 32 * 64; o += 256) {
        int nn = o >> 6, j = o & 63;
        float acc = b1[j];
        for (int k = 0; k < 128; k++) acc = fmaf(s_h[nn][k], s_w1[k * 64 + j], acc);
        s_hid[nn][j] = fmaxf(acc, 0.f);
    }
    __syncthreads();
    int nn = t >> 3, kk = t & 7;
    int gn = n0 + nn;
    float a = b2[kk];
    for (int j = 0; j < 64; j++) a = fmaf(s_hid[nn][j], s_w2[j * 8 + kk], a);
    if (gn < N) a += gum[(size_t)gn * 8 + kk];
    float m = a;
    m = fmaxf(m, __shfl_xor(m, 1));
    m = fmaxf(m, __shfl_xor(m, 2));
    m = fmaxf(m, __shfl_xor(m, 4));
    float e = expf(a - m);
    float s = e;
    s += __shfl_xor(s, 1); s += __shfl_xor(s, 2); s += __shfl_xor(s, 4);
    if (gn < N) assign[(size_t)gn * 8 + kk] = e / s;
}

// ---------------- fused tail: BN-relu + pool + blob + LN + max + clf1 -------
__device__ __forceinline__ int lowerb(const int* __restrict__ arr, int n, int val) {
    int lo = 0, hi = n;
    while (lo < hi) {
        int mid = (lo + hi) >> 1;
        if (arr[mid] < val) lo = mid + 1;
        else hi = mid;
    }
    return lo;
}

__global__ __launch_bounds__(1024) void k_tail(
    const float* __restrict__ t2f, const float* __restrict__ bstats,
    const float* __restrict__ bng, const float* __restrict__ bnb, float invN,
    const float* __restrict__ assign,
    const int* __restrict__ batch, const float* __restrict__ bm_w,
    const float* __restrict__ bm_b, const float* __restrict__ ln_g,
    const float* __restrict__ ln_b, const float* __restrict__ clf1_w,
    const float* __restrict__ clf1_b, float* __restrict__ t4,
    float* __restrict__ stats, int N) {
    __shared__ float4 s_num[4][8][32];
    __shared__ float4 s_gm[4][32];
    __shared__ float s_den[4][8];
    __shared__ float s_numf[8][128];
    __shared__ float s_denf[8];
    __shared__ float s_blob[8][128];
    __shared__ float s_cat[256];
    __shared__ float s_r[16][2];
    const int g = blockIdx.x;
    const int t = threadIdx.x;
    const int ns = t >> 8;
    const int k = (t >> 5) & 7;
    const int lane = t & 31;
    const int c4 = lane << 2;
    const int start = lowerb(batch, N, g);
    const int end = lowerb(batch, N, g + 1);

    float bsc[4], bsh[4];
#pragma unroll
    for (int j = 0; j < 4; j++) {
        float m = bstats[c4 + j] * invN;
        float var = bstats[128 + c4 + j] * invN - m * m;
        float s = bng[c4 + j] * rsqrtf(var + 1e-5f);
        bsc[j] = s;
        bsh[j] = bnb[c4 + j] - m * s;
    }

    float4 an = {0.f, 0.f, 0.f, 0.f};
    float4 gm = {0.f, 0.f, 0.f, 0.f};
    float ad = 0.f;
    for (int n = start + ns; n < end; n += 4) {
        float a = assign[(size_t)n * 8 + k];
        float4 tv = *(const float4*)(t2f + (size_t)n * HH + c4);
        float4 hv;
        hv.x = fmaxf(tv.x * bsc[0] + bsh[0], 0.f);
        hv.y = fmaxf(tv.y * bsc[1] + bsh[1], 0.f);
        hv.z = fmaxf(tv.z * bsc[2] + bsh[2], 0.f);
        hv.w = fmaxf(tv.w * bsc[3] + bsh[3], 0.f);
        an.x = fmaf(a, hv.x, an.x);
        an.y = fmaf(a, hv.y, an.y);
        an.z = fmaf(a, hv.z, an.z);
        an.w = fmaf(a, hv.w, an.w);
        if (k == 0) { gm.x += hv.x; gm.y += hv.y; gm.z += hv.z; gm.w += hv.w; }
        ad += a;
    }
    s_num[ns][k][lane] = an;
    if (k == 0) s_gm[ns][lane] = gm;
    if (lane == 0) s_den[ns][k] = ad;
    __syncthreads();
    if (t < 256) {
        float4 a0 = s_num[0][k][lane], a1 = s_num[1][k][lane];
        float4 a2 = s_num[2][k][lane], a3 = s_num[3][k][lane];
        s_numf[k][c4 + 0] = a0.x + a1.x + a2.x + a3.x;
        s_numf[k][c4 + 1] = a0.y + a1.y + a2.y + a3.y;
        s_numf[k][c4 + 2] = a0.z + a1.z + a2.z + a3.z;
        s_numf[k][c4 + 3] = a0.w + a1.w + a2.w + a3.w;
        if (t < 32) {
            float4 g0 = s_gm[0][lane], g1 = s_gm[1][lane];
            float4 g2 = s_gm[2][lane], g3 = s_gm[3][lane];
            int cnt = end - start;
            float inv = 1.f / (float)(cnt > 0 ? cnt : 1);
            s_cat[c4 + 0] = (g0.x + g1.x + g2.x + g3.x) * inv;
            s_cat[c4 + 1] = (g0.y + g1.y + g2.y + g3.y) * inv;
            s_cat[c4 + 2] = (g0.z + g1.z + g2.z + g3.z) * inv;
            s_cat[c4 + 3] = (g0.w + g1.w + g2.w + g3.w) * inv;
        }
        if (t < 8) s_denf[t] = s_den[0][t] + s_den[1][t] + s_den[2][t] + s_den[3][t];
    }
    __syncthreads();

    {
        const int kk = t >> 7;
        const int c = t & 127;
        const float d = 1.f / (s_denf[kk] + 1e-8f);
        float acc = bm_b[c];
        for (int j = 0; j < 128; j++)
            acc = fmaf(s_numf[kk][j] * d, bm_w[j * HH + c], acc);
        float y = fmaxf(acc, 0.f);
        float s = y, q = y * y;
        for (int off = 32; off > 0; off >>= 1) {
            s += __shfl_down(s, off);
            q += __shfl_down(q, off);
        }
        const int wv = t >> 6;
        if ((t & 63) == 0) { s_r[wv][0] = s; s_r[wv][1] = q; }
        __syncthreads();
        float S = s_r[kk * 2][0] + s_r[kk * 2 + 1][0];
        float Q = s_r[kk * 2][1] + s_r[kk * 2 + 1][1];
        float m = S * (1.f / 128.f);
        float var = Q * (1.f / 128.f) - m * m;
        s_blob[kk][c] = (y - m) * rsqrtf(var + 1e-5f) * ln_g[c] + ln_b[c];
    }
    __syncthreads();

    if (t < 128) {
        float m = s_blob[0][t];
#pragma unroll
        for (int kk = 1; kk < 8; kk++) m = fmaxf(m, s_blob[kk][t]);
        s_cat[128 + t] = m;
    }
    __syncthreads();

    if (t < 128) {
        float acc = clf1_b[t];
        for (int j = 0; j < 256; j++) acc = fmaf(s_cat[j], clf1_w[j * HH + t], acc);
        t4[(size_t)g * HH + t] = acc;
        atomAddF(&stats[t], acc);
        atomAddF(&stats[HH + t], acc * acc);
    }
}

__global__ void k_clf2(const float* __restrict__ t4, const float* __restrict__ stats,
                       const float* __restrict__ g_, const float* __restrict__ b_,
                       float invG, const float* __restrict__ w,
                       const float* __restrict__ bias, float* __restrict__ out) {
    int g = blockIdx.x;
    int t = threadIdx.x;  // 128
    __shared__ float s[128];
    float m = stats[t] * invG;
    float var = stats[128 + t] * invG - m * m;
    float sc = g_[t] * rsqrtf(var + 1e-5f);
    float sh = b_[t] - m * sc;
    s[t] = fmaxf(t4[(size_t)g * HH + t] * sc + sh, 0.f);
    __syncthreads();
    if (t < 10) {
        float acc = bias[t];
        for (int j = 0; j < 128; j++) acc = fmaf(s[j], w[j * 10 + t], acc);
        out[(size_t)g * 10 + t] = acc;
    }
}

extern "C" void kernel_launch(void* const* d_in, const int* in_sizes, int n_in,
                              void* d_out, int out_size, void* d_ws, size_t ws_size,
                              hipStream_t stream) {
    const float* x      = (const float*)d_in[0];
    const int*   ei     = (const int*)d_in[1];
    const int*   batch  = (const int*)d_in[2];
    const float* gumbel = (const float*)d_in[3];
    const float* inp_w  = (const float*)d_in[4];
    const float* inp_b  = (const float*)d_in[5];
    const float* elin_w = (const float*)d_in[6];
    const float* elin_b = (const float*)d_in[7];
    const float* mlp1_w = (const float*)d_in[8];
    const float* mlp1_b = (const float*)d_in[9];
    const float* mlpbn_g = (const float*)d_in[10];
    const float* mlpbn_b = (const float*)d_in[11];
    const float* mlp2_w = (const float*)d_in[12];
    const float* mlp2_b = (const float*)d_in[13];
    const float* bn_g   = (const float*)d_in[14];
    const float* bn_b   = (const float*)d_in[15];
    const float* bh1_w  = (const float*)d_in[16];
    const float* bh1_b  = (const float*)d_in[17];
    const float* bh2_w  = (const float*)d_in[18];
    const float* bh2_b  = (const float*)d_in[19];
    const float* bm_w   = (const float*)d_in[20];
    const float* bm_b   = (const float*)d_in[21];
    const float* ln_g   = (const float*)d_in[22];
    const float* ln_b   = (const float*)d_in[23];
    const float* clf1_w = (const float*)d_in[24];
    const float* clf1_b = (const float*)d_in[25];
    const float* clfbn_g = (const float*)d_in[26];
    const float* clfbn_b = (const float*)d_in[27];
    const float* clf2_w = (const float*)d_in[28];
    const float* clf2_b = (const float*)d_in[29];
    float* out = (float*)d_out;

    const int N = in_sizes[0] / 64;
    const int E = in_sizes[1] / 2;
    const int G = out_size / 10;

    float* ws = (float*)d_ws;
    float* A      = ws;                                  // z (u16 hi/lo)
    float* B      = A + (size_t)N * HH;                  // t2b (u16) / t2 f32
    float* C      = B + (size_t)N * HH;                  // act0+hb (u16) / t1 f32
    float* assign = C + (size_t)N * HH;                  // N*8
    float* t4     = assign + (size_t)N * 8;              // G*128
    float* statsA = t4 + (size_t)G * HH;                 // 7*256
    u16* Whi = (u16*)(statsA + 7 * 256);                 // WTOT
    u16* Wlo = Whi + WTOT;                               // WTOT
    int* rowptr = (int*)(Wlo + WTOT);                    // N+1
    int* deg    = rowptr + (N + 1);                      // N
    int* colidx = deg + N;                               // E
    int* eorder = colidx + E;                            // E
    int* bsum   = eorder + E;                            // 256
    int* boff   = bsum + 256;                            // 256
    // aliases:
    u16* zhi  = (u16*)A;
    u16* zlo  = zhi + (size_t)N * HH;
    u16* t2b  = (u16*)B;
    float* t2f = B;
    u16* hb   = (u16*)C;   // act0 / per-layer bf16 h
    float* t1 = C;

    const dim3 B256(256), B128(128), B512(512), B1024(1024);
    const int ntiles = (N + 127) / 128;
    const int gg = ntiles < 512 ? ntiles : 512;
    const int nch = (N + 255) / 256;
    const int e4 = (E + 4 * 256 - 1) / (4 * 256);
    const float invN = 1.f / (float)N;
    const float invG = 1.f / (float)G;

    // weight prep + CSR build + stats clear
    k_prep<<<7, B256, 0, stream>>>(inp_w, mlp1_w, mlp2_w, Whi, Wlo);
    hipMemsetAsync(deg, 0, (size_t)N * sizeof(int), stream);
    hipMemsetAsync(statsA, 0, 7 * 256 * sizeof(float), stream);
    k_hist<<<e4, B256, 0, stream>>>(ei, deg, eorder, E);
    k_bsum<<<nch, B256, 0, stream>>>(deg, bsum, N);
    k_scan1<<<1, B256, 0, stream>>>(bsum, boff, rowptr + N, nch);
    k_scan2<<<nch, B256, 0, stream>>>(deg, boff, rowptr, N);
    k_fill<<<e4, B256, 0, stream>>>(ei, rowptr, eorder, colidx, E);

    // hb = bf16(x @ inp_w + inp_b)
    k_mgemm<64, 0, false, false, true><<<gg, B512, 0, stream>>>(
        x, nullptr, nullptr, Whi, Wlo, inp_b, nullptr, nullptr, nullptr, 0.f,
        nullptr, hb, nullptr, N, ntiles);

    for (int l = 0; l < 3; l++) {
        float* sa = statsA + (size_t)(2 * l) * 256;
        float* sb = sa + 256;
        k_gather<<<(N + 1) / 2, B256, 0, stream>>>(hb, rowptr, colidx,
                                                   elin_w + l * HH, elin_b + l * HH,
                                                   zhi, zlo, N);
        // t1 = z @ W1 + b1 (stats -> sa)
        k_mgemm<128, 2, true, true, false><<<gg, B512, 0, stream>>>(
            nullptr, zhi, zlo, Whi + 8192 + (size_t)l * 16384,
            Wlo + 8192 + (size_t)l * 16384, mlp1_b + l * HH,
            nullptr, nullptr, nullptr, 0.f, t1, nullptr, sa, N, ntiles);
        // t2 = relu(bn(t1)) @ W2 + b2 ; bf16 out for l<2, f32 for l==2
        if (l < 2) {
            k_mgemm<128, 1, true, false, true><<<gg, B512, 0, stream>>>(
                t1, nullptr, nullptr, Whi + 8192 + (size_t)(3 + l) * 16384,
                Wlo + 8192 + (size_t)(3 + l) * 16384, mlp2_b + l * HH,
                sa, mlpbn_g + l * HH, mlpbn_b + l * HH, invN,
                nullptr, t2b, sb, N, ntiles);
            k_bnrelu_bf<<<(N * 32 + 255) / 256, B256, 0, stream>>>(
                t2b, sb, bn_g + l * HH, bn_b + l * HH, invN, hb, N * 32);
        } else {
            k_mgemm<128, 1, true, true, false><<<gg, B512, 0, stream>>>(
                t1, nullptr, nullptr, Whi + 8192 + (size_t)(3 + l) * 16384,
                Wlo + 8192 + (size_t)(3 + l) * 16384, mlp2_b + l * HH,
                sa, mlpbn_g + l * HH, mlpbn_b + l * HH, invN,
                t2f, nullptr, sb, N, ntiles);
        }
    }

    float* sb2 = statsA + 5 * 256;   // stats of final t2
    k_assign<<<(N + 31) / 32, B256, 0, stream>>>(
        t2f, sb2, bn_g + 2 * HH, bn_b + 2 * HH, invN,
        gumbel, bh1_w, bh1_b, bh2_w, bh2_b, assign, N);
    float* sc_ = statsA + 6 * 256;
    k_tail<<<G, B1024, 0, stream>>>(t2f, sb2, bn_g + 2 * HH, bn_b + 2 * HH, invN,
                                    assign, batch, bm_w, bm_b, ln_g, ln_b,
                                    clf1_w, clf1_b, t4, sc_, N);
    k_clf2<<<G, B128, 0, stream>>>(t4, sc_, clfbn_g, clfbn_b, invG, clf2_w, clf2_b, out);
}